// Round 12
// baseline (396.608 us; speedup 1.0000x reference)
//
#include <hip/hip_runtime.h>
#include <hip/hip_bf16.h>
#include <stdint.h>

typedef __bf16 bf16;
typedef __bf16 bf16x8 __attribute__((ext_vector_type(8)));
typedef __bf16 bf16x4 __attribute__((ext_vector_type(4)));
typedef float  f32x4  __attribute__((ext_vector_type(4)));

#define DI __device__ __forceinline__

// ---------------- problem sizes ----------------
constexpr int ROWS = 4 * 4096;     // B*S = 16384
constexpr int HH   = 2048;
constexpr int MM   = 64;
constexpr int NHID = 1024;
constexpr int NC   = 1152;         // 64 scores + 1024 hidden + 64 pad

// ---------------- output layout (f32 elements) ----------------
constexpr size_t O_OUT  = 0;
constexpr size_t O_GATE = (size_t)ROWS * HH;
constexpr size_t O_MK   = O_GATE + ROWS;
constexpr size_t O_MV   = O_MK + (size_t)MM * HH;
constexpr size_t O_UC   = O_MV + (size_t)MM * HH;
constexpr size_t O_TS   = O_UC + MM;

// ---------------- ws layout (bytes) ----------------
constexpr size_t WS_XLB  = 0;                                    // bf16[16384*2048]; dead after main GEMM -> xpart bf16[512*2048]
constexpr size_t WS_C    = WS_XLB + (size_t)ROWS * HH * 2;       // bf16[16384*1152]
constexpr size_t WS_BMAT = WS_C + (size_t)ROWS * NC * 2;         // bf16[1152*2048]
constexpr size_t WS_WQT  = WS_BMAT + (size_t)NC * HH * 2;        // bf16[2048*2048]
constexpr size_t WS_W1B  = WS_WQT + (size_t)HH * HH * 2;         // bf16[1024*2048]
constexpr size_t WS_MKP  = WS_W1B + (size_t)NHID * HH * 2;       // bf16[128*2048]
constexpr size_t WS_MVP  = WS_MKP + (size_t)128 * HH * 2;        // bf16[128*2048]
constexpr size_t WS_Q2T  = WS_MVP + (size_t)128 * HH * 2;        // bf16[1024*64]
constexpr size_t WS_PF   = WS_Q2T + (size_t)NHID * MM * 2;       // f32[64*2048]
constexpr size_t WS_Q2F  = WS_PF + (size_t)MM * HH * 4;          // f32[64*1024]
constexpr size_t WS_CVEC = WS_Q2F + (size_t)MM * NHID * 4;       // f32[64]
constexpr size_t WS_XBAR = WS_CVEC + 64 * 4;                     // f32[4*2048]
constexpr size_t WS_KB   = WS_XBAR + (size_t)4 * HH * 4;         // f32[4*2048]
constexpr size_t WS_VB   = WS_KB + (size_t)4 * HH * 4;           // f32[4*2048]
constexpr size_t WS_MVT  = WS_VB + (size_t)4 * HH * 4;           // bf16[2048*64]

DI void gload16(const void* g, void* l) {
    __builtin_amdgcn_global_load_lds((__attribute__((address_space(1))) void*)g,
                                     (__attribute__((address_space(3))) void*)l,
                                     16, 0, 0);
}

DI bf16x8 cvt8(f32x4 a, f32x4 b) {
    bf16x8 v;
    v[0]=(bf16)a[0]; v[1]=(bf16)a[1]; v[2]=(bf16)a[2]; v[3]=(bf16)a[3];
    v[4]=(bf16)b[0]; v[5]=(bf16)b[1]; v[6]=(bf16)b[2]; v[7]=(bf16)b[3];
    return v;
}

DI float wave_sum(float v) {
#pragma unroll
    for (int off = 32; off; off >>= 1) v += __shfl_xor(v, off);
    return v;
}

// =================================================================
// GEMM: C[M,N] = A[M,K] @ Bt[N,K]^T   (128x128 tile, BK=64, bf16 in)
// LDS XOR-swizzle + XCD-chunked remap (verified rounds 3-11)
// =================================================================
template <bool SPLITK, bool REMAP>
__global__ __launch_bounds__(256)
void gemm_bt(const bf16* __restrict__ A, int lda,
             const bf16* __restrict__ Bt, int ldb,
             void* __restrict__ Cv, int ldc,
             int Mmax, int kit)
{
    __shared__ __align__(16) bf16 As[128 * 64];
    __shared__ __align__(16) bf16 Bs[128 * 64];
    const int tid  = threadIdx.x;
    const int wid  = tid >> 6, lane = tid & 63;
    int bx, by;
    if (REMAP) {                      // grid = 1152 linear, 9 n-tiles, 128 m-tiles
        int bid = blockIdx.x;
        int xcd = bid & 7, loc = bid >> 3;   // 144 tiles per XCD
        bx = xcd * 16 + loc / 9;
        by = loc % 9;
    } else { bx = blockIdx.x; by = blockIdx.y; }
    const int m0   = bx * 128, n0 = by * 128;
    const int wr   = wid >> 1, wc = wid & 1;
    const int kt0  = blockIdx.z * kit;
    const int srow  = lane >> 3;
    const int sslot = (lane & 7) ^ srow;

    f32x4 acc[4][4] = {};

    for (int kt = kt0; kt < kt0 + kit; ++kt) {
        const bf16* Ak = A + (size_t)kt * 64;
        const bf16* Bk = Bt + (size_t)kt * 64;
#pragma unroll
        for (int c = 0; c < 4; ++c) {
            int ch  = wid * 4 + c;
            int row = ch * 8 + srow;
            gload16(Ak + (size_t)(m0 + row) * lda + sslot * 8, As + ch * 512);
        }
#pragma unroll
        for (int c = 0; c < 4; ++c) {
            int ch  = wid * 4 + c;
            int row = ch * 8 + srow;
            gload16(Bk + (size_t)(n0 + row) * ldb + sslot * 8, Bs + ch * 512);
        }
        __syncthreads();
#pragma unroll
        for (int ks = 0; ks < 2; ++ks) {
            bf16x8 av[4], bv[4];
#pragma unroll
            for (int mi = 0; mi < 4; ++mi) {
                int r = wr * 64 + mi * 16 + (lane & 15);
                int slot = ((ks * 4 + (lane >> 4)) ^ (r & 7)) * 8;
                av[mi] = *(const bf16x8*)&As[r * 64 + slot];
            }
#pragma unroll
            for (int ni = 0; ni < 4; ++ni) {
                int r = wc * 64 + ni * 16 + (lane & 15);
                int slot = ((ks * 4 + (lane >> 4)) ^ (r & 7)) * 8;
                bv[ni] = *(const bf16x8*)&Bs[r * 64 + slot];
            }
#pragma unroll
            for (int mi = 0; mi < 4; ++mi)
#pragma unroll
                for (int ni = 0; ni < 4; ++ni)
                    acc[mi][ni] = __builtin_amdgcn_mfma_f32_16x16x32_bf16(
                        av[mi], bv[ni], acc[mi][ni], 0, 0, 0);
        }
        __syncthreads();
    }

#pragma unroll
    for (int mi = 0; mi < 4; ++mi) {
#pragma unroll
        for (int ni = 0; ni < 4; ++ni) {
            int col = n0 + wc * 64 + ni * 16 + (lane & 15);
#pragma unroll
            for (int j = 0; j < 4; ++j) {
                int row = m0 + wr * 64 + mi * 16 + (lane >> 4) * 4 + j;
                if (row < Mmax) {
                    if (SPLITK)
                        atomicAdd((float*)Cv + (size_t)row * ldc + col, acc[mi][ni][j]);
                    else
                        ((bf16*)Cv)[(size_t)row * ldc + col] = (bf16)acc[mi][ni][j];
                }
            }
        }
    }
}

// xl (f32) -> xlb (bf16)
__global__ __launch_bounds__(256)
void conv_xl_k(const float* __restrict__ xl, bf16* __restrict__ xlb)
{
    size_t idx = ((size_t)blockIdx.x * 256 + threadIdx.x) * 8;
    f32x4 a = *(const f32x4*)&xl[idx];
    f32x4 b = *(const f32x4*)&xl[idx + 4];
    *(bf16x8*)&xlb[idx] = cvt8(a, b);
}

// Wq (f32 [o][i]) -> WqT (bf16 [i][o])
__global__ __launch_bounds__(256)
void transpose_k(const float* __restrict__ src, bf16* __restrict__ dst)
{
    __shared__ float T[64][72];
    const int o0 = blockIdx.y * 64, i0 = blockIdx.x * 64;
    const int t = threadIdx.x, r = t >> 3, c8 = (t & 7) * 8;
#pragma unroll
    for (int rep = 0; rep < 2; ++rep) {
        int row = r + rep * 32;
        *(f32x4*)&T[row][c8]     = *(const f32x4*)&src[(size_t)(o0 + row) * HH + i0 + c8];
        *(f32x4*)&T[row][c8 + 4] = *(const f32x4*)&src[(size_t)(o0 + row) * HH + i0 + c8 + 4];
    }
    __syncthreads();
#pragma unroll
    for (int rep = 0; rep < 2; ++rep) {
        int irow = r + rep * 32;
        bf16x8 v;
#pragma unroll
        for (int jj = 0; jj < 8; ++jj) v[jj] = (bf16)T[c8 + jj][irow];
        *(bf16x8*)&dst[(size_t)(i0 + irow) * HH + o0 + c8] = v;
    }
}

// mk/mv (f32 [64,2048]) -> mkP/mvP (bf16 [128,2048], zero pad)
__global__ __launch_bounds__(256)
void padcpy_k(const float* __restrict__ mk, const float* __restrict__ mv,
              bf16* __restrict__ mkP, bf16* __restrict__ mvP)
{
    int idx = (blockIdx.x * 256 + threadIdx.x) * 8;
    const int half = 128 * HH;
    const float* s; bf16* d; int i;
    if (idx < half) { i = idx; d = mkP; s = mk; }
    else            { i = idx - half; d = mvP; s = mv; }
    bf16x8 v = {};
    if (i < MM * HH) {
        f32x4 a = *(const f32x4*)&s[i];
        f32x4 b = *(const f32x4*)&s[i + 4];
        v = cvt8(a, b);
    }
    *(bf16x8*)&d[i] = v;
}

// Bmat rows 64..1151 <- Wg1[:, :2048] (bf16), zero pad; also W1b <- Wg1[:, 2048:]
__global__ __launch_bounds__(256)
void bmatfill_k(const float* __restrict__ Wg1, bf16* __restrict__ Bmat, bf16* __restrict__ W1b)
{
    int row = 64 + blockIdx.x;           // 64..1151
    int c8  = threadIdx.x * 8;
    int j   = row - 64;
    bf16x8 v = {};
    if (j < NHID) {
        f32x4 a = *(const f32x4*)&Wg1[(size_t)j * 4096 + c8];
        f32x4 b = *(const f32x4*)&Wg1[(size_t)j * 4096 + c8 + 4];
        v = cvt8(a, b);
        f32x4 c = *(const f32x4*)&Wg1[(size_t)j * 4096 + 2048 + c8];
        f32x4 d = *(const f32x4*)&Wg1[(size_t)j * 4096 + 2048 + c8 + 4];
        *(bf16x8*)&W1b[(size_t)j * HH + c8] = cvt8(c, d);
    }
    *(bf16x8*)&Bmat[(size_t)row * HH + c8] = v;
}

// cvec[m] = sum_o bq[o]*mk[m,o]   (64 blocks, one per m)
__global__ __launch_bounds__(256)
void cvec_k(const float* __restrict__ bq, const float* __restrict__ mk, float* __restrict__ cvec)
{
    __shared__ float wS[4];
    const int m = blockIdx.x, t = threadIdx.x, wid = t >> 6, lane = t & 63;
    const int o0 = t * 8;
    f32x4 b0 = *(const f32x4*)&bq[o0];
    f32x4 b1 = *(const f32x4*)&bq[o0 + 4];
    f32x4 k0 = *(const f32x4*)&mk[(size_t)m * HH + o0];
    f32x4 k1 = *(const f32x4*)&mk[(size_t)m * HH + o0 + 4];
    float acc = b0[0]*k0[0] + b0[1]*k0[1] + b0[2]*k0[2] + b0[3]*k0[3]
              + b1[0]*k1[0] + b1[1]*k1[1] + b1[2]*k1[2] + b1[3]*k1[3];
    acc = wave_sum(acc);
    if (lane == 0) wS[wid] = acc;
    __syncthreads();
    if (t == 0) cvec[m] = wS[0] + wS[1] + wS[2] + wS[3];
}

// merged: Pf->Bmat rows 0..63 ; Q2f -> q2t (transposed bf16) ; mv -> mvT
__global__ __launch_bounds__(256)
void prep2_k(const float* __restrict__ Pf, bf16* __restrict__ Bmat,
             const float* __restrict__ Q2f, const float* __restrict__ mv,
             bf16* __restrict__ q2t, bf16* __restrict__ mvT)
{
    int gid = blockIdx.x * 256 + threadIdx.x;
    if (gid < 16384) {                       // Pf -> Bmat (x8 vectorized)
        int idx = gid * 8;
        f32x4 a = *(const f32x4*)&Pf[idx];
        f32x4 b = *(const f32x4*)&Pf[idx + 4];
        *(bf16x8*)&Bmat[idx] = cvt8(a, b);
    } else if (gid < 16384 + NHID * MM) {    // q2t[j][m] = Q2f[m][j]
        int idx = gid - 16384;
        int j = idx >> 6, m = idx & 63;
        q2t[idx] = (bf16)Q2f[(size_t)m * NHID + j];
    } else {                                 // mvT[h][m] = mv[m][h]
        int i = gid - 16384 - NHID * MM;
        int h = i >> 6, m = i & 63;
        mvT[i] = (bf16)mv[(size_t)m * HH + h];
    }
}

// =================================================================
// MFMA epilogue v7: 32 rows/block, 512 blocks, 512 THREADS (8 waves)
// -> 16 waves/CU. Two 16-row A-groups share each B-fragment load;
// per-wave column span halved vs v6. Two-pass LN (verified).
// =================================================================
__global__ __launch_bounds__(512)
void epi_k(const bf16* __restrict__ Cb, const float* __restrict__ cvec,
           const bf16* __restrict__ mvT, const bf16* __restrict__ q2t,
           const float* __restrict__ chs,
           const float* __restrict__ bg1, const float* __restrict__ w2,
           const float* __restrict__ bg2,
           const float* __restrict__ gamma, const float* __restrict__ beta,
           float* __restrict__ out, bf16* __restrict__ xpart)
{
    __shared__ __align__(16) bf16 attnB[32 * 64];
    __shared__ float redA[8][32], redB[8][32];
    __shared__ float gS[32], muS[32], rsS[32];
    const int t = threadIdx.x, wid = t >> 6, lane = t & 63;
    const size_t row0 = (size_t)blockIdx.x * 32;
    const int cl = lane & 15;
    const int rbase = (lane >> 4) * 4;

    // ---- phase 1: softmax; wave w -> rows 4w..4w+3
    {
        float cv = cvec[lane];
#pragma unroll
        for (int rr = 0; rr < 4; ++rr) {
            int r = wid * 4 + rr;
            float s = (float)Cb[(row0 + r) * NC + lane] + cv;
            float mx = s;
#pragma unroll
            for (int off = 32; off; off >>= 1) mx = fmaxf(mx, __shfl_xor(mx, off));
            float e = expf(s - mx);
            float sum = e;
#pragma unroll
            for (int off = 32; off; off >>= 1) sum += __shfl_xor(sum, off);
            attnB[r * 64 + lane] = (bf16)(e / sum);
        }
    }
    __syncthreads();

    // A-fragments for both 16-row groups (verified layout)
    bf16x8 av00 = *(const bf16x8*)&attnB[(cl)      * 64 +  0 + (lane >> 4) * 8];
    bf16x8 av01 = *(const bf16x8*)&attnB[(cl)      * 64 + 32 + (lane >> 4) * 8];
    bf16x8 av10 = *(const bf16x8*)&attnB[(16 + cl) * 64 +  0 + (lane >> 4) * 8];
    bf16x8 av11 = *(const bf16x8*)&attnB[(16 + cl) * 64 + 32 + (lane >> 4) * 8];

    // ---- phase 2: gate — one B-load feeds both groups (8 waves x 128 cols)
    {
        float gp[2][4] = {};
#pragma unroll
        for (int nt = 0; nt < 8; ++nt) {
            int ct = wid * 128 + nt * 16 + cl;
            bf16x8 bv0 = *(const bf16x8*)&q2t[(size_t)ct * 64 +  0 + (lane >> 4) * 8];
            bf16x8 bv1 = *(const bf16x8*)&q2t[(size_t)ct * 64 + 32 + (lane >> 4) * 8];
            float b1 = bg1[ct], wv = w2[ct];
            f32x4 a0 = {}, a1 = {};
            a0 = __builtin_amdgcn_mfma_f32_16x16x32_bf16(av00, bv0, a0, 0, 0, 0);
            a0 = __builtin_amdgcn_mfma_f32_16x16x32_bf16(av01, bv1, a0, 0, 0, 0);
            a1 = __builtin_amdgcn_mfma_f32_16x16x32_bf16(av10, bv0, a1, 0, 0, 0);
            a1 = __builtin_amdgcn_mfma_f32_16x16x32_bf16(av11, bv1, a1, 0, 0, 0);
#pragma unroll
            for (int j = 0; j < 4; ++j) {
                float c0 = (float)Cb[(row0 + rbase + j) * NC + 64 + ct];
                float c1 = (float)Cb[(row0 + 16 + rbase + j) * NC + 64 + ct];
                gp[0][j] += fmaxf(c0 + b1 + a0[j], 0.f) * wv;
                gp[1][j] += fmaxf(c1 + b1 + a1[j], 0.f) * wv;
            }
        }
#pragma unroll
        for (int g = 0; g < 2; ++g)
#pragma unroll
            for (int j = 0; j < 4; ++j) {
                gp[g][j] += __shfl_xor(gp[g][j], 1);
                gp[g][j] += __shfl_xor(gp[g][j], 2);
                gp[g][j] += __shfl_xor(gp[g][j], 4);
                gp[g][j] += __shfl_xor(gp[g][j], 8);
            }
        if (cl == 0) {
#pragma unroll
            for (int g = 0; g < 2; ++g)
#pragma unroll
                for (int j = 0; j < 4; ++j) redA[wid][g * 16 + rbase + j] = gp[g][j];
        }
    }
    __syncthreads();
    if (t < 32) {
        float g = redA[0][t] + redA[1][t] + redA[2][t] + redA[3][t]
                + redA[4][t] + redA[5][t] + redA[6][t] + redA[7][t];
        g = 1.f / (1.f + expf(-(g + bg2[0])));
        gS[t] = g;
        out[O_GATE + row0 + t] = g;
    }
    __syncthreads();

    float gR[2][4], omR[2][4];
#pragma unroll
    for (int g = 0; g < 2; ++g)
#pragma unroll
        for (int j = 0; j < 4; ++j) { gR[g][j] = gS[g * 16 + rbase + j]; omR[g][j] = 1.f - gR[g][j]; }

    // ---- phase 3 (pass A): retrieved MFMA + fuse -> LN stats + xpart
    {
        float sA[2][4] = {}, qA[2][4] = {};
#pragma unroll
        for (int nt = 0; nt < 16; ++nt) {
            int ct = wid * 256 + nt * 16 + cl;
            bf16x8 bv0 = *(const bf16x8*)&mvT[(size_t)ct * 64 +  0 + (lane >> 4) * 8];
            bf16x8 bv1 = *(const bf16x8*)&mvT[(size_t)ct * 64 + 32 + (lane >> 4) * 8];
            f32x4 a0 = {}, a1 = {};
            a0 = __builtin_amdgcn_mfma_f32_16x16x32_bf16(av00, bv0, a0, 0, 0, 0);
            a0 = __builtin_amdgcn_mfma_f32_16x16x32_bf16(av01, bv1, a0, 0, 0, 0);
            a1 = __builtin_amdgcn_mfma_f32_16x16x32_bf16(av10, bv0, a1, 0, 0, 0);
            a1 = __builtin_amdgcn_mfma_f32_16x16x32_bf16(av11, bv1, a1, 0, 0, 0);
            float xc = 0.f;
#pragma unroll
            for (int j = 0; j < 4; ++j) {
                float x0 = chs[(row0 + rbase + j) * HH + ct];
                float x1 = chs[(row0 + 16 + rbase + j) * HH + ct];
                xc += x0 + x1;
                float f0 = omR[0][j] * x0 + gR[0][j] * a0[j];
                float f1 = omR[1][j] * x1 + gR[1][j] * a1[j];
                sA[0][j] += f0; qA[0][j] += f0 * f0;
                sA[1][j] += f1; qA[1][j] += f1 * f1;
            }
            xc += __shfl_xor(xc, 16);
            xc += __shfl_xor(xc, 32);
            if (lane < 16) xpart[(size_t)blockIdx.x * 2048 + ct] = (bf16)xc;
        }
#pragma unroll
        for (int g = 0; g < 2; ++g)
#pragma unroll
            for (int j = 0; j < 4; ++j) {
                sA[g][j] += __shfl_xor(sA[g][j], 1); qA[g][j] += __shfl_xor(qA[g][j], 1);
                sA[g][j] += __shfl_xor(sA[g][j], 2); qA[g][j] += __shfl_xor(qA[g][j], 2);
                sA[g][j] += __shfl_xor(sA[g][j], 4); qA[g][j] += __shfl_xor(qA[g][j], 4);
                sA[g][j] += __shfl_xor(sA[g][j], 8); qA[g][j] += __shfl_xor(qA[g][j], 8);
            }
        if (cl == 0) {
#pragma unroll
            for (int g = 0; g < 2; ++g)
#pragma unroll
                for (int j = 0; j < 4; ++j) {
                    redA[wid][g * 16 + rbase + j] = sA[g][j];
                    redB[wid][g * 16 + rbase + j] = qA[g][j];
                }
        }
    }
    __syncthreads();
    if (t < 32) {
        float s = redA[0][t] + redA[1][t] + redA[2][t] + redA[3][t]
                + redA[4][t] + redA[5][t] + redA[6][t] + redA[7][t];
        float q = redB[0][t] + redB[1][t] + redB[2][t] + redB[3][t]
                + redB[4][t] + redB[5][t] + redB[6][t] + redB[7][t];
        float mu  = s * (1.f / 2048.f);
        float var = q * (1.f / 2048.f) - mu * mu;
        muS[t] = mu;
        rsS[t] = rsqrtf(var + 1e-5f);
    }
    __syncthreads();

    float muR[2][4], rsR[2][4];
#pragma unroll
    for (int g = 0; g < 2; ++g)
#pragma unroll
        for (int j = 0; j < 4; ++j) { muR[g][j] = muS[g * 16 + rbase + j]; rsR[g][j] = rsS[g * 16 + rbase + j]; }

    // ---- phase 4 (pass B): recompute (L2-hot) + write normalized output
#pragma unroll
    for (int nt = 0; nt < 16; ++nt) {
        int ct = wid * 256 + nt * 16 + cl;
        bf16x8 bv0 = *(const bf16x8*)&mvT[(size_t)ct * 64 +  0 + (lane >> 4) * 8];
        bf16x8 bv1 = *(const bf16x8*)&mvT[(size_t)ct * 64 + 32 + (lane >> 4) * 8];
        f32x4 a0 = {}, a1 = {};
        a0 = __builtin_amdgcn_mfma_f32_16x16x32_bf16(av00, bv0, a0, 0, 0, 0);
        a0 = __builtin_amdgcn_mfma_f32_16x16x32_bf16(av01, bv1, a0, 0, 0, 0);
        a1 = __builtin_amdgcn_mfma_f32_16x16x32_bf16(av10, bv0, a1, 0, 0, 0);
        a1 = __builtin_amdgcn_mfma_f32_16x16x32_bf16(av11, bv1, a1, 0, 0, 0);
        float ga = gamma[ct], be = beta[ct];
#pragma unroll
        for (int j = 0; j < 4; ++j) {
            float x0 = chs[(row0 + rbase + j) * HH + ct];
            float x1 = chs[(row0 + 16 + rbase + j) * HH + ct];
            float f0 = omR[0][j] * x0 + gR[0][j] * a0[j];
            float f1 = omR[1][j] * x1 + gR[1][j] * a1[j];
            out[O_OUT + (row0 + rbase + j) * HH + ct]      = (f0 - muR[0][j]) * rsR[0][j] * ga + be;
            out[O_OUT + (row0 + 16 + rbase + j) * HH + ct] = (f1 - muR[1][j]) * rsR[1][j] * ga + be;
        }
    }
}

// xbar[b][h] = sum over 128 block-partials (bf16) per batch
__global__ __launch_bounds__(256)
void xred_k(const bf16* __restrict__ xpart, float* __restrict__ xbar)
{
    int o = blockIdx.x * 256 + threadIdx.x;   // 0..8191
    int b = o >> 11, h = o & 2047;
    const bf16* p = xpart + (size_t)(b * 128) * 2048 + h;
    float acc = 0.f;
    for (int k = 0; k < 128; ++k) acc += (float)p[(size_t)k * 2048];
    xbar[o] = acc;
}

// kb/vb[b,h] = bias[h] + (1/4096) * sum_i xbar[b,i]*W[h,i]  (4-way i-split)
__global__ __launch_bounds__(256)
void kbvb_k(const float* __restrict__ xbar,
            const float* __restrict__ Wk, const float* __restrict__ bk,
            const float* __restrict__ Wv, const float* __restrict__ bv,
            float* __restrict__ kb, float* __restrict__ vb)
{
    int gt = blockIdx.x * 256 + threadIdx.x;    // 0..65535
    int out_idx = gt >> 2, part = gt & 3;
    int mat = out_idx >> 13, rem = out_idx & 8191;
    int b = rem >> 11, h = rem & 2047;
    const float* W    = mat ? Wv : Wk;
    const float* bias = mat ? bv : bk;
    const float* x    = xbar + b * HH;
    float acc = 0.f;
    const int i0 = part * 512;
    for (int i = i0; i < i0 + 512; i += 8) {
        f32x4 w0 = *(const f32x4*)&W[(size_t)h * HH + i];
        f32x4 w1 = *(const f32x4*)&W[(size_t)h * HH + i + 4];
        f32x4 x0 = *(const f32x4*)&x[i];
        f32x4 x1 = *(const f32x4*)&x[i + 4];
        acc += x0[0]*w0[0] + x0[1]*w0[1] + x0[2]*w0[2] + x0[3]*w0[3];
        acc += x1[0]*w1[0] + x1[1]*w1[1] + x1[2]*w1[2] + x1[3]*w1[3];
    }
    acc += __shfl_xor(acc, 1);
    acc += __shfl_xor(acc, 2);
    if (part == 0)
        (mat ? vb : kb)[b * HH + h] = bias[h] + acc * (1.f / 4096.f);
}

// copy mk/mv inputs (f32) to output slots (f32)
__global__ __launch_bounds__(256)
void copy_mkmv_k(const float* __restrict__ mk, const float* __restrict__ mv, float* __restrict__ out)
{
    int idx = (blockIdx.x * 256 + threadIdx.x) * 4;
    const int half = MM * HH;
    if (idx < half)
        *(f32x4*)&out[O_MK + idx] = *(const f32x4*)&mk[idx];
    else
        *(f32x4*)&out[O_MV + (idx - half)] = *(const f32x4*)&mv[idx - half];
}

// sequential argmin-scatter memory update (4 steps), single block
__global__ __launch_bounds__(256)
void scan_k(const int* __restrict__ uc_in, const int* __restrict__ ts_in,
            const float* __restrict__ kb, const float* __restrict__ vb,
            float* __restrict__ out)
{
    __shared__ int ucS[64], tsS[64];
    __shared__ int idxS, tmaxS;
    const int t = threadIdx.x;
    if (t < 64) { ucS[t] = uc_in[t]; tsS[t] = ts_in[t]; }
    __syncthreads();
    for (int b = 0; b < 4; ++b) {
        if (t < 64) {
            float bs = (float)ucS[t] + 0.1f * (float)tsS[t];
            int bi = t;
            int tm = tsS[t];
#pragma unroll
            for (int off = 1; off < 64; off <<= 1) {
                float os = __shfl_xor(bs, off);
                int   oi = __shfl_xor(bi, off);
                int   om = __shfl_xor(tm, off);
                if (os < bs || (os == bs && oi < bi)) { bs = os; bi = oi; }
                tm = max(tm, om);
            }
            if (t == 0) { idxS = bi; tmaxS = tm; }
        }
        __syncthreads();
        int idx = idxS;
        int e = t * 8;
        *(f32x4*)&out[O_MK + (size_t)idx * HH + e]     = *(const f32x4*)&kb[b * HH + e];
        *(f32x4*)&out[O_MK + (size_t)idx * HH + e + 4] = *(const f32x4*)&kb[b * HH + e + 4];
        *(f32x4*)&out[O_MV + (size_t)idx * HH + e]     = *(const f32x4*)&vb[b * HH + e];
        *(f32x4*)&out[O_MV + (size_t)idx * HH + e + 4] = *(const f32x4*)&vb[b * HH + e + 4];
        __syncthreads();
        if (t == 0) { ucS[idx] += 1; tsS[idx] = tmaxS + 1; }
        __syncthreads();
    }
    if (t < 64) {
        out[O_UC + t] = (float)ucS[t];
        out[O_TS + t] = (float)tsS[t];
    }
}

// =================================================================
extern "C" void kernel_launch(void* const* d_in, const int* in_sizes, int n_in,
                              void* d_out, int out_size, void* d_ws, size_t ws_size,
                              hipStream_t stream)
{
    const float* chs = (const float*)d_in[0];
    const float* xl  = (const float*)d_in[1];
    const float* mk  = (const float*)d_in[2];
    const float* mv  = (const float*)d_in[3];
    const float* Wq  = (const float*)d_in[4];
    const float* bq  = (const float*)d_in[5];
    const float* Wk  = (const float*)d_in[6];
    const float* bk  = (const float*)d_in[7];
    const float* Wv  = (const float*)d_in[8];
    const float* bv  = (const float*)d_in[9];
    const float* Wg1 = (const float*)d_in[10];
    const float* bg1 = (const float*)d_in[11];
    const float* Wg2 = (const float*)d_in[12];
    const float* bg2 = (const float*)d_in[13];
    const float* lng = (const float*)d_in[14];
    const float* lnb = (const float*)d_in[15];
    const int*   ucI = (const int*)d_in[16];
    const int*   tsI = (const int*)d_in[17];

    uint8_t* ws = (uint8_t*)d_ws;
    float* outp = (float*)d_out;

    bf16*  xlb  = (bf16*)(ws + WS_XLB);
    bf16*  xpart= (bf16*)(ws + WS_XLB);     // reuse: xlb dead after main GEMM
    bf16*  Cb   = (bf16*)(ws + WS_C);
    bf16*  Bmat = (bf16*)(ws + WS_BMAT);
    bf16*  WqT  = (bf16*)(ws + WS_WQT);
    bf16*  W1b  = (bf16*)(ws + WS_W1B);
    bf16*  mkP  = (bf16*)(ws + WS_MKP);
    bf16*  mvP  = (bf16*)(ws + WS_MVP);
    bf16*  q2t  = (bf16*)(ws + WS_Q2T);
    bf16*  mvT  = (bf16*)(ws + WS_MVT);
    float* Pf   = (float*)(ws + WS_PF);
    float* Q2f  = (float*)(ws + WS_Q2F);
    float* cvec = (float*)(ws + WS_CVEC);
    float* xbar = (float*)(ws + WS_XBAR);
    float* kb   = (float*)(ws + WS_KB);
    float* vb   = (float*)(ws + WS_VB);

    hipMemsetAsync(Pf, 0, (size_t)MM * HH * 4, stream);
    hipMemsetAsync(Q2f, 0, (size_t)MM * NHID * 4, stream);

    conv_xl_k<<<16384, 256, 0, stream>>>(xl, xlb);
    transpose_k<<<dim3(32, 32), 256, 0, stream>>>(Wq, WqT);
    padcpy_k<<<256, 256, 0, stream>>>(mk, mv, mkP, mvP);
    bmatfill_k<<<1088, 256, 0, stream>>>(Wg1, Bmat, W1b);
    cvec_k<<<64, 256, 0, stream>>>(bq, mk, cvec);

    // P = mkPad @ Wq  (split-K, f32 atomic)
    gemm_bt<true, false><<<dim3(1, 16, 8), 256, 0, stream>>>(mkP, HH, WqT, HH, Pf, HH, MM, 4);
    // Q2 = mvPad @ Wg1b^T
    gemm_bt<true, false><<<dim3(1, 8, 8), 256, 0, stream>>>(mvP, HH, W1b, HH, Q2f, NHID, MM, 4);
    prep2_k<<<832, 256, 0, stream>>>(Pf, Bmat, Q2f, mv, q2t, mvT);

    // main fused GEMM: [16384,2048] @ [2048,1152]  (XCD-chunked remap)
    gemm_bt<false, true><<<1152, 256, 0, stream>>>(xlb, HH, Bmat, HH, Cb, NC, ROWS, 32);

    epi_k<<<512, 512, 0, stream>>>(Cb, cvec, mvT, q2t, chs, bg1, Wg2, bg2, lng, lnb, outp, xpart);

    xred_k<<<32, 256, 0, stream>>>(xpart, xbar);
    kbvb_k<<<256, 256, 0, stream>>>(xbar, Wk, bk, Wv, bv, kb, vb);
    copy_mkmv_k<<<256, 256, 0, stream>>>(mk, mv, outp);
    scan_k<<<1, 256, 0, stream>>>(ucI, tsI, kb, vb, outp);
}

// Round 13
// 361.076 us; speedup vs baseline: 1.0984x; 1.0984x over previous
//
#include <hip/hip_runtime.h>
#include <hip/hip_bf16.h>
#include <stdint.h>

typedef __bf16 bf16;
typedef __bf16 bf16x8 __attribute__((ext_vector_type(8)));
typedef __bf16 bf16x4 __attribute__((ext_vector_type(4)));
typedef float  f32x4  __attribute__((ext_vector_type(4)));

#define DI __device__ __forceinline__

// ---------------- problem sizes ----------------
constexpr int ROWS = 4 * 4096;     // B*S = 16384
constexpr int HH   = 2048;
constexpr int MM   = 64;
constexpr int NHID = 1024;
constexpr int NC   = 1152;         // 64 scores + 1024 hidden + 64 pad

// ---------------- output layout (f32 elements) ----------------
constexpr size_t O_OUT  = 0;
constexpr size_t O_GATE = (size_t)ROWS * HH;
constexpr size_t O_MK   = O_GATE + ROWS;
constexpr size_t O_MV   = O_MK + (size_t)MM * HH;
constexpr size_t O_UC   = O_MV + (size_t)MM * HH;
constexpr size_t O_TS   = O_UC + MM;

// ---------------- ws layout (bytes) ----------------
constexpr size_t WS_XPART= 0;                                    // bf16[512*2048] xbar partials
constexpr size_t WS_C    = WS_XPART + (size_t)ROWS * HH * 2;     // bf16[16384*1152]
constexpr size_t WS_BMAT = WS_C + (size_t)ROWS * NC * 2;         // bf16[1152*2048]
constexpr size_t WS_WQT  = WS_BMAT + (size_t)NC * HH * 2;        // bf16[2048*2048]
constexpr size_t WS_W1B  = WS_WQT + (size_t)HH * HH * 2;         // bf16[1024*2048]
constexpr size_t WS_MKP  = WS_W1B + (size_t)NHID * HH * 2;       // bf16[128*2048]
constexpr size_t WS_MVP  = WS_MKP + (size_t)128 * HH * 2;        // bf16[128*2048]
constexpr size_t WS_Q2T  = WS_MVP + (size_t)128 * HH * 2;        // bf16[1024*64]
constexpr size_t WS_PF   = WS_Q2T + (size_t)NHID * MM * 2;       // f32[64*2048]
constexpr size_t WS_Q2F  = WS_PF + (size_t)MM * HH * 4;          // f32[64*1024]
constexpr size_t WS_CVEC = WS_Q2F + (size_t)MM * NHID * 4;       // f32[64]
constexpr size_t WS_XBAR = WS_CVEC + 64 * 4;                     // f32[4*2048]
constexpr size_t WS_KB   = WS_XBAR + (size_t)4 * HH * 4;         // f32[4*2048]
constexpr size_t WS_VB   = WS_KB + (size_t)4 * HH * 4;           // f32[4*2048]
constexpr size_t WS_MVT  = WS_VB + (size_t)4 * HH * 4;           // bf16[2048*64]

DI void gload16(const void* g, void* l) {
    __builtin_amdgcn_global_load_lds((__attribute__((address_space(1))) void*)g,
                                     (__attribute__((address_space(3))) void*)l,
                                     16, 0, 0);
}

DI bf16x8 cvt8(f32x4 a, f32x4 b) {
    bf16x8 v;
    v[0]=(bf16)a[0]; v[1]=(bf16)a[1]; v[2]=(bf16)a[2]; v[3]=(bf16)a[3];
    v[4]=(bf16)b[0]; v[5]=(bf16)b[1]; v[6]=(bf16)b[2]; v[7]=(bf16)b[3];
    return v;
}

DI float wave_sum(float v) {
#pragma unroll
    for (int off = 32; off; off >>= 1) v += __shfl_xor(v, off);
    return v;
}

// =================================================================
// GEMM: C[M,N] = A[M,K] @ Bt[N,K]^T   (128x128 tile, BK=64, bf16 in)
// LDS XOR-swizzle + XCD-chunked remap (verified rounds 3-12).
// AF32: A is f32, reg-staged with conversion into the SAME LDS slot
// layout gload16 produced (As[ch*512 + lane*8]) — read side unchanged.
// =================================================================
template <bool SPLITK, bool REMAP, bool AF32>
__global__ __launch_bounds__(256)
void gemm_bt(const void* __restrict__ Av, int lda,
             const bf16* __restrict__ Bt, int ldb,
             void* __restrict__ Cv, int ldc,
             int Mmax, int kit)
{
    __shared__ __align__(16) bf16 As[128 * 64];
    __shared__ __align__(16) bf16 Bs[128 * 64];
    const int tid  = threadIdx.x;
    const int wid  = tid >> 6, lane = tid & 63;
    int bx, by;
    if (REMAP) {                      // grid = 1152 linear, 9 n-tiles, 128 m-tiles
        int bid = blockIdx.x;
        int xcd = bid & 7, loc = bid >> 3;   // 144 tiles per XCD
        bx = xcd * 16 + loc / 9;
        by = loc % 9;
    } else { bx = blockIdx.x; by = blockIdx.y; }
    const int m0   = bx * 128, n0 = by * 128;
    const int wr   = wid >> 1, wc = wid & 1;
    const int kt0  = blockIdx.z * kit;
    const int srow  = lane >> 3;
    const int sslot = (lane & 7) ^ srow;

    f32x4 acc[4][4] = {};

    for (int kt = kt0; kt < kt0 + kit; ++kt) {
        const bf16* Bk = Bt + (size_t)kt * 64;
        if (AF32) {
            const float* Ak = (const float*)Av + (size_t)kt * 64;
#pragma unroll
            for (int c = 0; c < 4; ++c) {
                int ch  = wid * 4 + c;
                int row = ch * 8 + srow;
                const float* src = Ak + (size_t)(m0 + row) * lda + sslot * 8;
                f32x4 a = *(const f32x4*)src;
                f32x4 b = *(const f32x4*)(src + 4);
                *(bf16x8*)&As[ch * 512 + lane * 8] = cvt8(a, b);
            }
        } else {
            const bf16* Ak = (const bf16*)Av + (size_t)kt * 64;
#pragma unroll
            for (int c = 0; c < 4; ++c) {
                int ch  = wid * 4 + c;
                int row = ch * 8 + srow;
                gload16(Ak + (size_t)(m0 + row) * lda + sslot * 8, As + ch * 512);
            }
        }
#pragma unroll
        for (int c = 0; c < 4; ++c) {
            int ch  = wid * 4 + c;
            int row = ch * 8 + srow;
            gload16(Bk + (size_t)(n0 + row) * ldb + sslot * 8, Bs + ch * 512);
        }
        __syncthreads();
#pragma unroll
        for (int ks = 0; ks < 2; ++ks) {
            bf16x8 av[4], bv[4];
#pragma unroll
            for (int mi = 0; mi < 4; ++mi) {
                int r = wr * 64 + mi * 16 + (lane & 15);
                int slot = ((ks * 4 + (lane >> 4)) ^ (r & 7)) * 8;
                av[mi] = *(const bf16x8*)&As[r * 64 + slot];
            }
#pragma unroll
            for (int ni = 0; ni < 4; ++ni) {
                int r = wc * 64 + ni * 16 + (lane & 15);
                int slot = ((ks * 4 + (lane >> 4)) ^ (r & 7)) * 8;
                bv[ni] = *(const bf16x8*)&Bs[r * 64 + slot];
            }
#pragma unroll
            for (int mi = 0; mi < 4; ++mi)
#pragma unroll
                for (int ni = 0; ni < 4; ++ni)
                    acc[mi][ni] = __builtin_amdgcn_mfma_f32_16x16x32_bf16(
                        av[mi], bv[ni], acc[mi][ni], 0, 0, 0);
        }
        __syncthreads();
    }

#pragma unroll
    for (int mi = 0; mi < 4; ++mi) {
#pragma unroll
        for (int ni = 0; ni < 4; ++ni) {
            int col = n0 + wc * 64 + ni * 16 + (lane & 15);
#pragma unroll
            for (int j = 0; j < 4; ++j) {
                int row = m0 + wr * 64 + mi * 16 + (lane >> 4) * 4 + j;
                if (row < Mmax) {
                    if (SPLITK)
                        atomicAdd((float*)Cv + (size_t)row * ldc + col, acc[mi][ni][j]);
                    else
                        ((bf16*)Cv)[(size_t)row * ldc + col] = (bf16)acc[mi][ni][j];
                }
            }
        }
    }
}

// Wq (f32 [o][i]) -> WqT (bf16 [i][o])
__global__ __launch_bounds__(256)
void transpose_k(const float* __restrict__ src, bf16* __restrict__ dst)
{
    __shared__ float T[64][72];
    const int o0 = blockIdx.y * 64, i0 = blockIdx.x * 64;
    const int t = threadIdx.x, r = t >> 3, c8 = (t & 7) * 8;
#pragma unroll
    for (int rep = 0; rep < 2; ++rep) {
        int row = r + rep * 32;
        *(f32x4*)&T[row][c8]     = *(const f32x4*)&src[(size_t)(o0 + row) * HH + i0 + c8];
        *(f32x4*)&T[row][c8 + 4] = *(const f32x4*)&src[(size_t)(o0 + row) * HH + i0 + c8 + 4];
    }
    __syncthreads();
#pragma unroll
    for (int rep = 0; rep < 2; ++rep) {
        int irow = r + rep * 32;
        bf16x8 v;
#pragma unroll
        for (int jj = 0; jj < 8; ++jj) v[jj] = (bf16)T[c8 + jj][irow];
        *(bf16x8*)&dst[(size_t)(i0 + irow) * HH + o0 + c8] = v;
    }
}

// mk/mv (f32 [64,2048]) -> mkP/mvP (bf16 [128,2048], zero pad)
__global__ __launch_bounds__(256)
void padcpy_k(const float* __restrict__ mk, const float* __restrict__ mv,
              bf16* __restrict__ mkP, bf16* __restrict__ mvP)
{
    int idx = (blockIdx.x * 256 + threadIdx.x) * 8;
    const int half = 128 * HH;
    const float* s; bf16* d; int i;
    if (idx < half) { i = idx; d = mkP; s = mk; }
    else            { i = idx - half; d = mvP; s = mv; }
    bf16x8 v = {};
    if (i < MM * HH) {
        f32x4 a = *(const f32x4*)&s[i];
        f32x4 b = *(const f32x4*)&s[i + 4];
        v = cvt8(a, b);
    }
    *(bf16x8*)&d[i] = v;
}

// Bmat rows 64..1151 <- Wg1[:, :2048] (bf16), zero pad; also W1b <- Wg1[:, 2048:]
__global__ __launch_bounds__(256)
void bmatfill_k(const float* __restrict__ Wg1, bf16* __restrict__ Bmat, bf16* __restrict__ W1b)
{
    int row = 64 + blockIdx.x;           // 64..1151
    int c8  = threadIdx.x * 8;
    int j   = row - 64;
    bf16x8 v = {};
    if (j < NHID) {
        f32x4 a = *(const f32x4*)&Wg1[(size_t)j * 4096 + c8];
        f32x4 b = *(const f32x4*)&Wg1[(size_t)j * 4096 + c8 + 4];
        v = cvt8(a, b);
        f32x4 c = *(const f32x4*)&Wg1[(size_t)j * 4096 + 2048 + c8];
        f32x4 d = *(const f32x4*)&Wg1[(size_t)j * 4096 + 2048 + c8 + 4];
        *(bf16x8*)&W1b[(size_t)j * HH + c8] = cvt8(c, d);
    }
    *(bf16x8*)&Bmat[(size_t)row * HH + c8] = v;
}

// cvec[m] = sum_o bq[o]*mk[m,o]   (64 blocks, one per m)
__global__ __launch_bounds__(256)
void cvec_k(const float* __restrict__ bq, const float* __restrict__ mk, float* __restrict__ cvec)
{
    __shared__ float wS[4];
    const int m = blockIdx.x, t = threadIdx.x, wid = t >> 6, lane = t & 63;
    const int o0 = t * 8;
    f32x4 b0 = *(const f32x4*)&bq[o0];
    f32x4 b1 = *(const f32x4*)&bq[o0 + 4];
    f32x4 k0 = *(const f32x4*)&mk[(size_t)m * HH + o0];
    f32x4 k1 = *(const f32x4*)&mk[(size_t)m * HH + o0 + 4];
    float acc = b0[0]*k0[0] + b0[1]*k0[1] + b0[2]*k0[2] + b0[3]*k0[3]
              + b1[0]*k1[0] + b1[1]*k1[1] + b1[2]*k1[2] + b1[3]*k1[3];
    acc = wave_sum(acc);
    if (lane == 0) wS[wid] = acc;
    __syncthreads();
    if (t == 0) cvec[m] = wS[0] + wS[1] + wS[2] + wS[3];
}

// merged: Pf->Bmat rows 0..63 ; Q2f -> q2t (transposed bf16) ; mv -> mvT
__global__ __launch_bounds__(256)
void prep2_k(const float* __restrict__ Pf, bf16* __restrict__ Bmat,
             const float* __restrict__ Q2f, const float* __restrict__ mv,
             bf16* __restrict__ q2t, bf16* __restrict__ mvT)
{
    int gid = blockIdx.x * 256 + threadIdx.x;
    if (gid < 16384) {                       // Pf -> Bmat (x8 vectorized)
        int idx = gid * 8;
        f32x4 a = *(const f32x4*)&Pf[idx];
        f32x4 b = *(const f32x4*)&Pf[idx + 4];
        *(bf16x8*)&Bmat[idx] = cvt8(a, b);
    } else if (gid < 16384 + NHID * MM) {    // q2t[j][m] = Q2f[m][j]
        int idx = gid - 16384;
        int j = idx >> 6, m = idx & 63;
        q2t[idx] = (bf16)Q2f[(size_t)m * NHID + j];
    } else {                                 // mvT[h][m] = mv[m][h]
        int i = gid - 16384 - NHID * MM;
        int h = i >> 6, m = i & 63;
        mvT[i] = (bf16)mv[(size_t)m * HH + h];
    }
}

// =================================================================
// MFMA epilogue v6 (r11-verified best): 32 rows/block, 512 blocks,
// 256 threads. Two 16-row A-groups share each B-fragment load.
// Two-pass LN.
// =================================================================
__global__ __launch_bounds__(256)
void epi_k(const bf16* __restrict__ Cb, const float* __restrict__ cvec,
           const bf16* __restrict__ mvT, const bf16* __restrict__ q2t,
           const float* __restrict__ chs,
           const float* __restrict__ bg1, const float* __restrict__ w2,
           const float* __restrict__ bg2,
           const float* __restrict__ gamma, const float* __restrict__ beta,
           float* __restrict__ out, bf16* __restrict__ xpart)
{
    __shared__ __align__(16) bf16 attnB[32 * 64];
    __shared__ float redA[4][32], redB[4][32];
    __shared__ float gS[32], muS[32], rsS[32];
    const int t = threadIdx.x, wid = t >> 6, lane = t & 63;
    const size_t row0 = (size_t)blockIdx.x * 32;
    const int cl = lane & 15;
    const int rbase = (lane >> 4) * 4;

    // ---- phase 1: softmax; wave w -> rows 8w..8w+7
    {
        float cv = cvec[lane];
#pragma unroll
        for (int rr = 0; rr < 8; ++rr) {
            int r = wid * 8 + rr;
            float s = (float)Cb[(row0 + r) * NC + lane] + cv;
            float mx = s;
#pragma unroll
            for (int off = 32; off; off >>= 1) mx = fmaxf(mx, __shfl_xor(mx, off));
            float e = expf(s - mx);
            float sum = e;
#pragma unroll
            for (int off = 32; off; off >>= 1) sum += __shfl_xor(sum, off);
            attnB[r * 64 + lane] = (bf16)(e / sum);
        }
    }
    __syncthreads();

    // A-fragments for both 16-row groups (verified layout)
    bf16x8 av00 = *(const bf16x8*)&attnB[(cl)      * 64 +  0 + (lane >> 4) * 8];
    bf16x8 av01 = *(const bf16x8*)&attnB[(cl)      * 64 + 32 + (lane >> 4) * 8];
    bf16x8 av10 = *(const bf16x8*)&attnB[(16 + cl) * 64 +  0 + (lane >> 4) * 8];
    bf16x8 av11 = *(const bf16x8*)&attnB[(16 + cl) * 64 + 32 + (lane >> 4) * 8];

    // ---- phase 2: gate — one B-load feeds both groups
    {
        float gp[2][4] = {};
#pragma unroll
        for (int nt = 0; nt < 16; ++nt) {
            int ct = wid * 256 + nt * 16 + cl;
            bf16x8 bv0 = *(const bf16x8*)&q2t[(size_t)ct * 64 +  0 + (lane >> 4) * 8];
            bf16x8 bv1 = *(const bf16x8*)&q2t[(size_t)ct * 64 + 32 + (lane >> 4) * 8];
            float b1 = bg1[ct], wv = w2[ct];
            f32x4 a0 = {}, a1 = {};
            a0 = __builtin_amdgcn_mfma_f32_16x16x32_bf16(av00, bv0, a0, 0, 0, 0);
            a0 = __builtin_amdgcn_mfma_f32_16x16x32_bf16(av01, bv1, a0, 0, 0, 0);
            a1 = __builtin_amdgcn_mfma_f32_16x16x32_bf16(av10, bv0, a1, 0, 0, 0);
            a1 = __builtin_amdgcn_mfma_f32_16x16x32_bf16(av11, bv1, a1, 0, 0, 0);
#pragma unroll
            for (int j = 0; j < 4; ++j) {
                float c0 = (float)Cb[(row0 + rbase + j) * NC + 64 + ct];
                float c1 = (float)Cb[(row0 + 16 + rbase + j) * NC + 64 + ct];
                gp[0][j] += fmaxf(c0 + b1 + a0[j], 0.f) * wv;
                gp[1][j] += fmaxf(c1 + b1 + a1[j], 0.f) * wv;
            }
        }
#pragma unroll
        for (int g = 0; g < 2; ++g)
#pragma unroll
            for (int j = 0; j < 4; ++j) {
                gp[g][j] += __shfl_xor(gp[g][j], 1);
                gp[g][j] += __shfl_xor(gp[g][j], 2);
                gp[g][j] += __shfl_xor(gp[g][j], 4);
                gp[g][j] += __shfl_xor(gp[g][j], 8);
            }
        if (cl == 0) {
#pragma unroll
            for (int g = 0; g < 2; ++g)
#pragma unroll
                for (int j = 0; j < 4; ++j) redA[wid][g * 16 + rbase + j] = gp[g][j];
        }
    }
    __syncthreads();
    if (t < 32) {
        float g = redA[0][t] + redA[1][t] + redA[2][t] + redA[3][t];
        g = 1.f / (1.f + expf(-(g + bg2[0])));
        gS[t] = g;
        out[O_GATE + row0 + t] = g;
    }
    __syncthreads();

    float gR[2][4], omR[2][4];
#pragma unroll
    for (int g = 0; g < 2; ++g)
#pragma unroll
        for (int j = 0; j < 4; ++j) { gR[g][j] = gS[g * 16 + rbase + j]; omR[g][j] = 1.f - gR[g][j]; }

    // ---- phase 3 (pass A): retrieved MFMA + fuse -> LN stats + xpart
    {
        float sA[2][4] = {}, qA[2][4] = {};
        for (int nt = 0; nt < 32; ++nt) {
            int ct = wid * 512 + nt * 16 + cl;
            bf16x8 bv0 = *(const bf16x8*)&mvT[(size_t)ct * 64 +  0 + (lane >> 4) * 8];
            bf16x8 bv1 = *(const bf16x8*)&mvT[(size_t)ct * 64 + 32 + (lane >> 4) * 8];
            f32x4 a0 = {}, a1 = {};
            a0 = __builtin_amdgcn_mfma_f32_16x16x32_bf16(av00, bv0, a0, 0, 0, 0);
            a0 = __builtin_amdgcn_mfma_f32_16x16x32_bf16(av01, bv1, a0, 0, 0, 0);
            a1 = __builtin_amdgcn_mfma_f32_16x16x32_bf16(av10, bv0, a1, 0, 0, 0);
            a1 = __builtin_amdgcn_mfma_f32_16x16x32_bf16(av11, bv1, a1, 0, 0, 0);
            float xc = 0.f;
#pragma unroll
            for (int j = 0; j < 4; ++j) {
                float x0 = chs[(row0 + rbase + j) * HH + ct];
                float x1 = chs[(row0 + 16 + rbase + j) * HH + ct];
                xc += x0 + x1;
                float f0 = omR[0][j] * x0 + gR[0][j] * a0[j];
                float f1 = omR[1][j] * x1 + gR[1][j] * a1[j];
                sA[0][j] += f0; qA[0][j] += f0 * f0;
                sA[1][j] += f1; qA[1][j] += f1 * f1;
            }
            xc += __shfl_xor(xc, 16);
            xc += __shfl_xor(xc, 32);
            if (lane < 16) xpart[(size_t)blockIdx.x * 2048 + ct] = (bf16)xc;
        }
#pragma unroll
        for (int g = 0; g < 2; ++g)
#pragma unroll
            for (int j = 0; j < 4; ++j) {
                sA[g][j] += __shfl_xor(sA[g][j], 1); qA[g][j] += __shfl_xor(qA[g][j], 1);
                sA[g][j] += __shfl_xor(sA[g][j], 2); qA[g][j] += __shfl_xor(qA[g][j], 2);
                sA[g][j] += __shfl_xor(sA[g][j], 4); qA[g][j] += __shfl_xor(qA[g][j], 4);
                sA[g][j] += __shfl_xor(sA[g][j], 8); qA[g][j] += __shfl_xor(qA[g][j], 8);
            }
        if (cl == 0) {
#pragma unroll
            for (int g = 0; g < 2; ++g)
#pragma unroll
                for (int j = 0; j < 4; ++j) {
                    redA[wid][g * 16 + rbase + j] = sA[g][j];
                    redB[wid][g * 16 + rbase + j] = qA[g][j];
                }
        }
    }
    __syncthreads();
    if (t < 32) {
        float s = redA[0][t] + redA[1][t] + redA[2][t] + redA[3][t];
        float q = redB[0][t] + redB[1][t] + redB[2][t] + redB[3][t];
        float mu  = s * (1.f / 2048.f);
        float var = q * (1.f / 2048.f) - mu * mu;
        muS[t] = mu;
        rsS[t] = rsqrtf(var + 1e-5f);
    }
    __syncthreads();

    float muR[2][4], rsR[2][4];
#pragma unroll
    for (int g = 0; g < 2; ++g)
#pragma unroll
        for (int j = 0; j < 4; ++j) { muR[g][j] = muS[g * 16 + rbase + j]; rsR[g][j] = rsS[g * 16 + rbase + j]; }

    // ---- phase 4 (pass B): recompute (L2-hot) + write normalized output
    for (int nt = 0; nt < 32; ++nt) {
        int ct = wid * 512 + nt * 16 + cl;
        bf16x8 bv0 = *(const bf16x8*)&mvT[(size_t)ct * 64 +  0 + (lane >> 4) * 8];
        bf16x8 bv1 = *(const bf16x8*)&mvT[(size_t)ct * 64 + 32 + (lane >> 4) * 8];
        f32x4 a0 = {}, a1 = {};
        a0 = __builtin_amdgcn_mfma_f32_16x16x32_bf16(av00, bv0, a0, 0, 0, 0);
        a0 = __builtin_amdgcn_mfma_f32_16x16x32_bf16(av01, bv1, a0, 0, 0, 0);
        a1 = __builtin_amdgcn_mfma_f32_16x16x32_bf16(av10, bv0, a1, 0, 0, 0);
        a1 = __builtin_amdgcn_mfma_f32_16x16x32_bf16(av11, bv1, a1, 0, 0, 0);
        float ga = gamma[ct], be = beta[ct];
#pragma unroll
        for (int j = 0; j < 4; ++j) {
            float x0 = chs[(row0 + rbase + j) * HH + ct];
            float x1 = chs[(row0 + 16 + rbase + j) * HH + ct];
            float f0 = omR[0][j] * x0 + gR[0][j] * a0[j];
            float f1 = omR[1][j] * x1 + gR[1][j] * a1[j];
            out[O_OUT + (row0 + rbase + j) * HH + ct]      = (f0 - muR[0][j]) * rsR[0][j] * ga + be;
            out[O_OUT + (row0 + 16 + rbase + j) * HH + ct] = (f1 - muR[1][j]) * rsR[1][j] * ga + be;
        }
    }
}

// xbar[b][h] = sum over 128 block-partials (bf16) per batch
__global__ __launch_bounds__(256)
void xred_k(const bf16* __restrict__ xpart, float* __restrict__ xbar)
{
    int o = blockIdx.x * 256 + threadIdx.x;   // 0..8191
    int b = o >> 11, h = o & 2047;
    const bf16* p = xpart + (size_t)(b * 128) * 2048 + h;
    float acc = 0.f;
    for (int k = 0; k < 128; ++k) acc += (float)p[(size_t)k * 2048];
    xbar[o] = acc;
}

// kb/vb[b,h] = bias[h] + (1/4096) * sum_i xbar[b,i]*W[h,i]  (4-way i-split)
__global__ __launch_bounds__(256)
void kbvb_k(const float* __restrict__ xbar,
            const float* __restrict__ Wk, const float* __restrict__ bk,
            const float* __restrict__ Wv, const float* __restrict__ bv,
            float* __restrict__ kb, float* __restrict__ vb)
{
    int gt = blockIdx.x * 256 + threadIdx.x;    // 0..65535
    int out_idx = gt >> 2, part = gt & 3;
    int mat = out_idx >> 13, rem = out_idx & 8191;
    int b = rem >> 11, h = rem & 2047;
    const float* W    = mat ? Wv : Wk;
    const float* bias = mat ? bv : bk;
    const float* x    = xbar + b * HH;
    float acc = 0.f;
    const int i0 = part * 512;
    for (int i = i0; i < i0 + 512; i += 8) {
        f32x4 w0 = *(const f32x4*)&W[(size_t)h * HH + i];
        f32x4 w1 = *(const f32x4*)&W[(size_t)h * HH + i + 4];
        f32x4 x0 = *(const f32x4*)&x[i];
        f32x4 x1 = *(const f32x4*)&x[i + 4];
        acc += x0[0]*w0[0] + x0[1]*w0[1] + x0[2]*w0[2] + x0[3]*w0[3];
        acc += x1[0]*w1[0] + x1[1]*w1[1] + x1[2]*w1[2] + x1[3]*w1[3];
    }
    acc += __shfl_xor(acc, 1);
    acc += __shfl_xor(acc, 2);
    if (part == 0)
        (mat ? vb : kb)[b * HH + h] = bias[h] + acc * (1.f / 4096.f);
}

// copy mk/mv inputs (f32) to output slots (f32)
__global__ __launch_bounds__(256)
void copy_mkmv_k(const float* __restrict__ mk, const float* __restrict__ mv, float* __restrict__ out)
{
    int idx = (blockIdx.x * 256 + threadIdx.x) * 4;
    const int half = MM * HH;
    if (idx < half)
        *(f32x4*)&out[O_MK + idx] = *(const f32x4*)&mk[idx];
    else
        *(f32x4*)&out[O_MV + (idx - half)] = *(const f32x4*)&mv[idx - half];
}

// sequential argmin-scatter memory update (4 steps), single block
__global__ __launch_bounds__(256)
void scan_k(const int* __restrict__ uc_in, const int* __restrict__ ts_in,
            const float* __restrict__ kb, const float* __restrict__ vb,
            float* __restrict__ out)
{
    __shared__ int ucS[64], tsS[64];
    __shared__ int idxS, tmaxS;
    const int t = threadIdx.x;
    if (t < 64) { ucS[t] = uc_in[t]; tsS[t] = ts_in[t]; }
    __syncthreads();
    for (int b = 0; b < 4; ++b) {
        if (t < 64) {
            float bs = (float)ucS[t] + 0.1f * (float)tsS[t];
            int bi = t;
            int tm = tsS[t];
#pragma unroll
            for (int off = 1; off < 64; off <<= 1) {
                float os = __shfl_xor(bs, off);
                int   oi = __shfl_xor(bi, off);
                int   om = __shfl_xor(tm, off);
                if (os < bs || (os == bs && oi < bi)) { bs = os; bi = oi; }
                tm = max(tm, om);
            }
            if (t == 0) { idxS = bi; tmaxS = tm; }
        }
        __syncthreads();
        int idx = idxS;
        int e = t * 8;
        *(f32x4*)&out[O_MK + (size_t)idx * HH + e]     = *(const f32x4*)&kb[b * HH + e];
        *(f32x4*)&out[O_MK + (size_t)idx * HH + e + 4] = *(const f32x4*)&kb[b * HH + e + 4];
        *(f32x4*)&out[O_MV + (size_t)idx * HH + e]     = *(const f32x4*)&vb[b * HH + e];
        *(f32x4*)&out[O_MV + (size_t)idx * HH + e + 4] = *(const f32x4*)&vb[b * HH + e + 4];
        __syncthreads();
        if (t == 0) { ucS[idx] += 1; tsS[idx] = tmaxS + 1; }
        __syncthreads();
    }
    if (t < 64) {
        out[O_UC + t] = (float)ucS[t];
        out[O_TS + t] = (float)tsS[t];
    }
}

// =================================================================
extern "C" void kernel_launch(void* const* d_in, const int* in_sizes, int n_in,
                              void* d_out, int out_size, void* d_ws, size_t ws_size,
                              hipStream_t stream)
{
    const float* chs = (const float*)d_in[0];
    const float* xl  = (const float*)d_in[1];
    const float* mk  = (const float*)d_in[2];
    const float* mv  = (const float*)d_in[3];
    const float* Wq  = (const float*)d_in[4];
    const float* bq  = (const float*)d_in[5];
    const float* Wk  = (const float*)d_in[6];
    const float* bk  = (const float*)d_in[7];
    const float* Wv  = (const float*)d_in[8];
    const float* bv  = (const float*)d_in[9];
    const float* Wg1 = (const float*)d_in[10];
    const float* bg1 = (const float*)d_in[11];
    const float* Wg2 = (const float*)d_in[12];
    const float* bg2 = (const float*)d_in[13];
    const float* lng = (const float*)d_in[14];
    const float* lnb = (const float*)d_in[15];
    const int*   ucI = (const int*)d_in[16];
    const int*   tsI = (const int*)d_in[17];

    uint8_t* ws = (uint8_t*)d_ws;
    float* outp = (float*)d_out;

    bf16*  xpart= (bf16*)(ws + WS_XPART);
    bf16*  Cb   = (bf16*)(ws + WS_C);
    bf16*  Bmat = (bf16*)(ws + WS_BMAT);
    bf16*  WqT  = (bf16*)(ws + WS_WQT);
    bf16*  W1b  = (bf16*)(ws + WS_W1B);
    bf16*  mkP  = (bf16*)(ws + WS_MKP);
    bf16*  mvP  = (bf16*)(ws + WS_MVP);
    bf16*  q2t  = (bf16*)(ws + WS_Q2T);
    bf16*  mvT  = (bf16*)(ws + WS_MVT);
    float* Pf   = (float*)(ws + WS_PF);
    float* Q2f  = (float*)(ws + WS_Q2F);
    float* cvec = (float*)(ws + WS_CVEC);
    float* xbar = (float*)(ws + WS_XBAR);
    float* kb   = (float*)(ws + WS_KB);
    float* vb   = (float*)(ws + WS_VB);

    hipMemsetAsync(Pf, 0, (size_t)MM * HH * 4, stream);
    hipMemsetAsync(Q2f, 0, (size_t)MM * NHID * 4, stream);

    transpose_k<<<dim3(32, 32), 256, 0, stream>>>(Wq, WqT);
    padcpy_k<<<256, 256, 0, stream>>>(mk, mv, mkP, mvP);
    bmatfill_k<<<1088, 256, 0, stream>>>(Wg1, Bmat, W1b);
    cvec_k<<<64, 256, 0, stream>>>(bq, mk, cvec);

    // P = mkPad @ Wq  (split-K, f32 atomic)
    gemm_bt<true, false, false><<<dim3(1, 16, 8), 256, 0, stream>>>(mkP, HH, WqT, HH, Pf, HH, MM, 4);
    // Q2 = mvPad @ Wg1b^T
    gemm_bt<true, false, false><<<dim3(1, 8, 8), 256, 0, stream>>>(mvP, HH, W1b, HH, Q2f, NHID, MM, 4);
    prep2_k<<<832, 256, 0, stream>>>(Pf, Bmat, Q2f, mv, q2t, mvT);

    // main fused GEMM: [16384,2048] @ [2048,1152]  (XCD remap, A=f32 direct)
    gemm_bt<false, true, true><<<1152, 256, 0, stream>>>(xl, HH, Bmat, HH, Cb, NC, ROWS, 32);

    epi_k<<<512, 256, 0, stream>>>(Cb, cvec, mvT, q2t, chs, bg1, Wg2, bg2, lng, lnb, outp, xpart);

    xred_k<<<32, 256, 0, stream>>>(xpart, xbar);
    kbvb_k<<<256, 256, 0, stream>>>(xbar, Wk, bk, Wv, bv, kb, vb);
    copy_mkmv_k<<<256, 256, 0, stream>>>(mk, mv, outp);
    scan_k<<<1, 256, 0, stream>>>(ucI, tsI, kb, vb, outp);
}

// Round 14
// 343.176 us; speedup vs baseline: 1.1557x; 1.0522x over previous
//
#include <hip/hip_runtime.h>
#include <hip/hip_bf16.h>
#include <stdint.h>

typedef __bf16 bf16;
typedef __bf16 bf16x8 __attribute__((ext_vector_type(8)));
typedef __bf16 bf16x4 __attribute__((ext_vector_type(4)));
typedef float  f32x4  __attribute__((ext_vector_type(4)));

#define DI __device__ __forceinline__

// ---------------- problem sizes ----------------
constexpr int ROWS = 4 * 4096;     // B*S = 16384
constexpr int HH   = 2048;
constexpr int MM   = 64;
constexpr int NHID = 1024;
constexpr int NC   = 1152;         // 64 scores + 1024 hidden + 64 pad

// ---------------- output layout (f32 elements) ----------------
constexpr size_t O_OUT  = 0;
constexpr size_t O_GATE = (size_t)ROWS * HH;
constexpr size_t O_MK   = O_GATE + ROWS;
constexpr size_t O_MV   = O_MK + (size_t)MM * HH;
constexpr size_t O_UC   = O_MV + (size_t)MM * HH;
constexpr size_t O_TS   = O_UC + MM;

// ---------------- ws layout (bytes) ----------------
constexpr size_t WS_XLB  = 0;                                    // bf16[16384*2048]; dead after main GEMM -> reused as fz bf16[16384*2048]
constexpr size_t WS_C    = WS_XLB + (size_t)ROWS * HH * 2;       // bf16[16384*1152]
constexpr size_t WS_BMAT = WS_C + (size_t)ROWS * NC * 2;         // bf16[1152*2048]
constexpr size_t WS_WQT  = WS_BMAT + (size_t)NC * HH * 2;        // bf16[2048*2048]; dead after P-GEMM -> xpart bf16[512*2048]
constexpr size_t WS_W1B  = WS_WQT + (size_t)HH * HH * 2;         // bf16[1024*2048]
constexpr size_t WS_MKP  = WS_W1B + (size_t)NHID * HH * 2;       // bf16[128*2048]
constexpr size_t WS_MVP  = WS_MKP + (size_t)128 * HH * 2;        // bf16[128*2048]
constexpr size_t WS_Q2T  = WS_MVP + (size_t)128 * HH * 2;        // bf16[1024*64]
constexpr size_t WS_PF   = WS_Q2T + (size_t)NHID * MM * 2;       // f32[64*2048]
constexpr size_t WS_Q2F  = WS_PF + (size_t)MM * HH * 4;          // f32[64*1024]
constexpr size_t WS_CVEC = WS_Q2F + (size_t)MM * NHID * 4;       // f32[64]
constexpr size_t WS_XBAR = WS_CVEC + 64 * 4;                     // f32[4*2048]
constexpr size_t WS_KB   = WS_XBAR + (size_t)4 * HH * 4;         // f32[4*2048]
constexpr size_t WS_VB   = WS_KB + (size_t)4 * HH * 4;           // f32[4*2048]
constexpr size_t WS_MVT  = WS_VB + (size_t)4 * HH * 4;           // bf16[2048*64]

DI void gload16(const void* g, void* l) {
    __builtin_amdgcn_global_load_lds((__attribute__((address_space(1))) void*)g,
                                     (__attribute__((address_space(3))) void*)l,
                                     16, 0, 0);
}

DI bf16x8 cvt8(f32x4 a, f32x4 b) {
    bf16x8 v;
    v[0]=(bf16)a[0]; v[1]=(bf16)a[1]; v[2]=(bf16)a[2]; v[3]=(bf16)a[3];
    v[4]=(bf16)b[0]; v[5]=(bf16)b[1]; v[6]=(bf16)b[2]; v[7]=(bf16)b[3];
    return v;
}

DI float wave_sum(float v) {
#pragma unroll
    for (int off = 32; off; off >>= 1) v += __shfl_xor(v, off);
    return v;
}

// =================================================================
// GEMM: C[M,N] = A[M,K] @ Bt[N,K]^T   (128x128 tile, BK=64, bf16 in)
// LDS XOR-swizzle + XCD-chunked remap (verified rounds 3-13)
// =================================================================
template <bool SPLITK, bool REMAP>
__global__ __launch_bounds__(256)
void gemm_bt(const bf16* __restrict__ A, int lda,
             const bf16* __restrict__ Bt, int ldb,
             void* __restrict__ Cv, int ldc,
             int Mmax, int kit)
{
    __shared__ __align__(16) bf16 As[128 * 64];
    __shared__ __align__(16) bf16 Bs[128 * 64];
    const int tid  = threadIdx.x;
    const int wid  = tid >> 6, lane = tid & 63;
    int bx, by;
    if (REMAP) {                      // grid = 1152 linear, 9 n-tiles, 128 m-tiles
        int bid = blockIdx.x;
        int xcd = bid & 7, loc = bid >> 3;   // 144 tiles per XCD
        bx = xcd * 16 + loc / 9;
        by = loc % 9;
    } else { bx = blockIdx.x; by = blockIdx.y; }
    const int m0   = bx * 128, n0 = by * 128;
    const int wr   = wid >> 1, wc = wid & 1;
    const int kt0  = blockIdx.z * kit;
    const int srow  = lane >> 3;
    const int sslot = (lane & 7) ^ srow;

    f32x4 acc[4][4] = {};

    for (int kt = kt0; kt < kt0 + kit; ++kt) {
        const bf16* Ak = A + (size_t)kt * 64;
        const bf16* Bk = Bt + (size_t)kt * 64;
#pragma unroll
        for (int c = 0; c < 4; ++c) {
            int ch  = wid * 4 + c;
            int row = ch * 8 + srow;
            gload16(Ak + (size_t)(m0 + row) * lda + sslot * 8, As + ch * 512);
        }
#pragma unroll
        for (int c = 0; c < 4; ++c) {
            int ch  = wid * 4 + c;
            int row = ch * 8 + srow;
            gload16(Bk + (size_t)(n0 + row) * ldb + sslot * 8, Bs + ch * 512);
        }
        __syncthreads();
#pragma unroll
        for (int ks = 0; ks < 2; ++ks) {
            bf16x8 av[4], bv[4];
#pragma unroll
            for (int mi = 0; mi < 4; ++mi) {
                int r = wr * 64 + mi * 16 + (lane & 15);
                int slot = ((ks * 4 + (lane >> 4)) ^ (r & 7)) * 8;
                av[mi] = *(const bf16x8*)&As[r * 64 + slot];
            }
#pragma unroll
            for (int ni = 0; ni < 4; ++ni) {
                int r = wc * 64 + ni * 16 + (lane & 15);
                int slot = ((ks * 4 + (lane >> 4)) ^ (r & 7)) * 8;
                bv[ni] = *(const bf16x8*)&Bs[r * 64 + slot];
            }
#pragma unroll
            for (int mi = 0; mi < 4; ++mi)
#pragma unroll
                for (int ni = 0; ni < 4; ++ni)
                    acc[mi][ni] = __builtin_amdgcn_mfma_f32_16x16x32_bf16(
                        av[mi], bv[ni], acc[mi][ni], 0, 0, 0);
        }
        __syncthreads();
    }

#pragma unroll
    for (int mi = 0; mi < 4; ++mi) {
#pragma unroll
        for (int ni = 0; ni < 4; ++ni) {
            int col = n0 + wc * 64 + ni * 16 + (lane & 15);
#pragma unroll
            for (int j = 0; j < 4; ++j) {
                int row = m0 + wr * 64 + mi * 16 + (lane >> 4) * 4 + j;
                if (row < Mmax) {
                    if (SPLITK)
                        atomicAdd((float*)Cv + (size_t)row * ldc + col, acc[mi][ni][j]);
                    else
                        ((bf16*)Cv)[(size_t)row * ldc + col] = (bf16)acc[mi][ni][j];
                }
            }
        }
    }
}

// xl (f32) -> xlb (bf16)
__global__ __launch_bounds__(256)
void conv_xl_k(const float* __restrict__ xl, bf16* __restrict__ xlb)
{
    size_t idx = ((size_t)blockIdx.x * 256 + threadIdx.x) * 8;
    f32x4 a = *(const f32x4*)&xl[idx];
    f32x4 b = *(const f32x4*)&xl[idx + 4];
    *(bf16x8*)&xlb[idx] = cvt8(a, b);
}

// Wq (f32 [o][i]) -> WqT (bf16 [i][o])
__global__ __launch_bounds__(256)
void transpose_k(const float* __restrict__ src, bf16* __restrict__ dst)
{
    __shared__ float T[64][72];
    const int o0 = blockIdx.y * 64, i0 = blockIdx.x * 64;
    const int t = threadIdx.x, r = t >> 3, c8 = (t & 7) * 8;
#pragma unroll
    for (int rep = 0; rep < 2; ++rep) {
        int row = r + rep * 32;
        *(f32x4*)&T[row][c8]     = *(const f32x4*)&src[(size_t)(o0 + row) * HH + i0 + c8];
        *(f32x4*)&T[row][c8 + 4] = *(const f32x4*)&src[(size_t)(o0 + row) * HH + i0 + c8 + 4];
    }
    __syncthreads();
#pragma unroll
    for (int rep = 0; rep < 2; ++rep) {
        int irow = r + rep * 32;
        bf16x8 v;
#pragma unroll
        for (int jj = 0; jj < 8; ++jj) v[jj] = (bf16)T[c8 + jj][irow];
        *(bf16x8*)&dst[(size_t)(i0 + irow) * HH + o0 + c8] = v;
    }
}

// mk/mv (f32 [64,2048]) -> mkP/mvP (bf16 [128,2048], zero pad)
__global__ __launch_bounds__(256)
void padcpy_k(const float* __restrict__ mk, const float* __restrict__ mv,
              bf16* __restrict__ mkP, bf16* __restrict__ mvP)
{
    int idx = (blockIdx.x * 256 + threadIdx.x) * 8;
    const int half = 128 * HH;
    const float* s; bf16* d; int i;
    if (idx < half) { i = idx; d = mkP; s = mk; }
    else            { i = idx - half; d = mvP; s = mv; }
    bf16x8 v = {};
    if (i < MM * HH) {
        f32x4 a = *(const f32x4*)&s[i];
        f32x4 b = *(const f32x4*)&s[i + 4];
        v = cvt8(a, b);
    }
    *(bf16x8*)&d[i] = v;
}

// Bmat rows 64..1151 <- Wg1[:, :2048] (bf16), zero pad; also W1b <- Wg1[:, 2048:]
__global__ __launch_bounds__(256)
void bmatfill_k(const float* __restrict__ Wg1, bf16* __restrict__ Bmat, bf16* __restrict__ W1b)
{
    int row = 64 + blockIdx.x;           // 64..1151
    int c8  = threadIdx.x * 8;
    int j   = row - 64;
    bf16x8 v = {};
    if (j < NHID) {
        f32x4 a = *(const f32x4*)&Wg1[(size_t)j * 4096 + c8];
        f32x4 b = *(const f32x4*)&Wg1[(size_t)j * 4096 + c8 + 4];
        v = cvt8(a, b);
        f32x4 c = *(const f32x4*)&Wg1[(size_t)j * 4096 + 2048 + c8];
        f32x4 d = *(const f32x4*)&Wg1[(size_t)j * 4096 + 2048 + c8 + 4];
        *(bf16x8*)&W1b[(size_t)j * HH + c8] = cvt8(c, d);
    }
    *(bf16x8*)&Bmat[(size_t)row * HH + c8] = v;
}

// cvec[m] = sum_o bq[o]*mk[m,o]   (64 blocks, one per m)
__global__ __launch_bounds__(256)
void cvec_k(const float* __restrict__ bq, const float* __restrict__ mk, float* __restrict__ cvec)
{
    __shared__ float wS[4];
    const int m = blockIdx.x, t = threadIdx.x, wid = t >> 6, lane = t & 63;
    const int o0 = t * 8;
    f32x4 b0 = *(const f32x4*)&bq[o0];
    f32x4 b1 = *(const f32x4*)&bq[o0 + 4];
    f32x4 k0 = *(const f32x4*)&mk[(size_t)m * HH + o0];
    f32x4 k1 = *(const f32x4*)&mk[(size_t)m * HH + o0 + 4];
    float acc = b0[0]*k0[0] + b0[1]*k0[1] + b0[2]*k0[2] + b0[3]*k0[3]
              + b1[0]*k1[0] + b1[1]*k1[1] + b1[2]*k1[2] + b1[3]*k1[3];
    acc = wave_sum(acc);
    if (lane == 0) wS[wid] = acc;
    __syncthreads();
    if (t == 0) cvec[m] = wS[0] + wS[1] + wS[2] + wS[3];
}

// merged: Pf->Bmat rows 0..63 ; Q2f -> q2t (transposed bf16) ; mv -> mvT
__global__ __launch_bounds__(256)
void prep2_k(const float* __restrict__ Pf, bf16* __restrict__ Bmat,
             const float* __restrict__ Q2f, const float* __restrict__ mv,
             bf16* __restrict__ q2t, bf16* __restrict__ mvT)
{
    int gid = blockIdx.x * 256 + threadIdx.x;
    if (gid < 16384) {                       // Pf -> Bmat (x8 vectorized)
        int idx = gid * 8;
        f32x4 a = *(const f32x4*)&Pf[idx];
        f32x4 b = *(const f32x4*)&Pf[idx + 4];
        *(bf16x8*)&Bmat[idx] = cvt8(a, b);
    } else if (gid < 16384 + NHID * MM) {    // q2t[j][m] = Q2f[m][j]
        int idx = gid - 16384;
        int j = idx >> 6, m = idx & 63;
        q2t[idx] = (bf16)Q2f[(size_t)m * NHID + j];
    } else {                                 // mvT[h][m] = mv[m][h]
        int i = gid - 16384 - NHID * MM;
        int h = i >> 6, m = i & 63;
        mvT[i] = (bf16)mv[(size_t)m * HH + h];
    }
}

// =================================================================
// MFMA epilogue v8: 32 rows/block, 512 blocks, 256 threads.
// Pass A: MFMA + fuse -> fz (bf16) to global scratch + LN stats + xpart.
// Pass B: read fz linearly, normalize, write out (no B-reads, no MFMA).
// =================================================================
__global__ __launch_bounds__(256)
void epi_k(const bf16* __restrict__ Cb, const float* __restrict__ cvec,
           const bf16* __restrict__ mvT, const bf16* __restrict__ q2t,
           const float* __restrict__ chs,
           const float* __restrict__ bg1, const float* __restrict__ w2,
           const float* __restrict__ bg2,
           const float* __restrict__ gamma, const float* __restrict__ beta,
           float* __restrict__ out, bf16* __restrict__ xpart,
           bf16* __restrict__ fz)
{
    __shared__ __align__(16) bf16 attnB[32 * 64];
    __shared__ float redA[4][32], redB[4][32];
    __shared__ float gS[32], muS[32], rsS[32];
    const int t = threadIdx.x, wid = t >> 6, lane = t & 63;
    const size_t row0 = (size_t)blockIdx.x * 32;
    const int cl = lane & 15;
    const int rbase = (lane >> 4) * 4;

    // ---- phase 1: softmax; wave w -> rows 8w..8w+7
    {
        float cv = cvec[lane];
#pragma unroll
        for (int rr = 0; rr < 8; ++rr) {
            int r = wid * 8 + rr;
            float s = (float)Cb[(row0 + r) * NC + lane] + cv;
            float mx = s;
#pragma unroll
            for (int off = 32; off; off >>= 1) mx = fmaxf(mx, __shfl_xor(mx, off));
            float e = expf(s - mx);
            float sum = e;
#pragma unroll
            for (int off = 32; off; off >>= 1) sum += __shfl_xor(sum, off);
            attnB[r * 64 + lane] = (bf16)(e / sum);
        }
    }
    __syncthreads();

    // A-fragments for both 16-row groups (verified layout)
    bf16x8 av00 = *(const bf16x8*)&attnB[(cl)      * 64 +  0 + (lane >> 4) * 8];
    bf16x8 av01 = *(const bf16x8*)&attnB[(cl)      * 64 + 32 + (lane >> 4) * 8];
    bf16x8 av10 = *(const bf16x8*)&attnB[(16 + cl) * 64 +  0 + (lane >> 4) * 8];
    bf16x8 av11 = *(const bf16x8*)&attnB[(16 + cl) * 64 + 32 + (lane >> 4) * 8];

    // ---- phase 2: gate — one B-load feeds both groups
    {
        float gp[2][4] = {};
#pragma unroll
        for (int nt = 0; nt < 16; ++nt) {
            int ct = wid * 256 + nt * 16 + cl;
            bf16x8 bv0 = *(const bf16x8*)&q2t[(size_t)ct * 64 +  0 + (lane >> 4) * 8];
            bf16x8 bv1 = *(const bf16x8*)&q2t[(size_t)ct * 64 + 32 + (lane >> 4) * 8];
            float b1 = bg1[ct], wv = w2[ct];
            f32x4 a0 = {}, a1 = {};
            a0 = __builtin_amdgcn_mfma_f32_16x16x32_bf16(av00, bv0, a0, 0, 0, 0);
            a0 = __builtin_amdgcn_mfma_f32_16x16x32_bf16(av01, bv1, a0, 0, 0, 0);
            a1 = __builtin_amdgcn_mfma_f32_16x16x32_bf16(av10, bv0, a1, 0, 0, 0);
            a1 = __builtin_amdgcn_mfma_f32_16x16x32_bf16(av11, bv1, a1, 0, 0, 0);
#pragma unroll
            for (int j = 0; j < 4; ++j) {
                float c0 = (float)Cb[(row0 + rbase + j) * NC + 64 + ct];
                float c1 = (float)Cb[(row0 + 16 + rbase + j) * NC + 64 + ct];
                gp[0][j] += fmaxf(c0 + b1 + a0[j], 0.f) * wv;
                gp[1][j] += fmaxf(c1 + b1 + a1[j], 0.f) * wv;
            }
        }
#pragma unroll
        for (int g = 0; g < 2; ++g)
#pragma unroll
            for (int j = 0; j < 4; ++j) {
                gp[g][j] += __shfl_xor(gp[g][j], 1);
                gp[g][j] += __shfl_xor(gp[g][j], 2);
                gp[g][j] += __shfl_xor(gp[g][j], 4);
                gp[g][j] += __shfl_xor(gp[g][j], 8);
            }
        if (cl == 0) {
#pragma unroll
            for (int g = 0; g < 2; ++g)
#pragma unroll
                for (int j = 0; j < 4; ++j) redA[wid][g * 16 + rbase + j] = gp[g][j];
        }
    }
    __syncthreads();
    if (t < 32) {
        float g = redA[0][t] + redA[1][t] + redA[2][t] + redA[3][t];
        g = 1.f / (1.f + expf(-(g + bg2[0])));
        gS[t] = g;
        out[O_GATE + row0 + t] = g;
    }
    __syncthreads();

    float gR[2][4], omR[2][4];
#pragma unroll
    for (int g = 0; g < 2; ++g)
#pragma unroll
        for (int j = 0; j < 4; ++j) { gR[g][j] = gS[g * 16 + rbase + j]; omR[g][j] = 1.f - gR[g][j]; }

    // ---- phase 3 (pass A): retrieved MFMA + fuse -> fz store + LN stats + xpart
    {
        float sA[2][4] = {}, qA[2][4] = {};
        for (int nt = 0; nt < 32; ++nt) {
            int ct = wid * 512 + nt * 16 + cl;
            bf16x8 bv0 = *(const bf16x8*)&mvT[(size_t)ct * 64 +  0 + (lane >> 4) * 8];
            bf16x8 bv1 = *(const bf16x8*)&mvT[(size_t)ct * 64 + 32 + (lane >> 4) * 8];
            f32x4 a0 = {}, a1 = {};
            a0 = __builtin_amdgcn_mfma_f32_16x16x32_bf16(av00, bv0, a0, 0, 0, 0);
            a0 = __builtin_amdgcn_mfma_f32_16x16x32_bf16(av01, bv1, a0, 0, 0, 0);
            a1 = __builtin_amdgcn_mfma_f32_16x16x32_bf16(av10, bv0, a1, 0, 0, 0);
            a1 = __builtin_amdgcn_mfma_f32_16x16x32_bf16(av11, bv1, a1, 0, 0, 0);
            float xc = 0.f;
#pragma unroll
            for (int j = 0; j < 4; ++j) {
                float x0 = chs[(row0 + rbase + j) * HH + ct];
                float x1 = chs[(row0 + 16 + rbase + j) * HH + ct];
                xc += x0 + x1;
                float f0 = omR[0][j] * x0 + gR[0][j] * a0[j];
                float f1 = omR[1][j] * x1 + gR[1][j] * a1[j];
                fz[(row0 + rbase + j) * HH + ct]      = (bf16)f0;
                fz[(row0 + 16 + rbase + j) * HH + ct] = (bf16)f1;
                sA[0][j] += f0; qA[0][j] += f0 * f0;
                sA[1][j] += f1; qA[1][j] += f1 * f1;
            }
            xc += __shfl_xor(xc, 16);
            xc += __shfl_xor(xc, 32);
            if (lane < 16) xpart[(size_t)blockIdx.x * 2048 + ct] = (bf16)xc;
        }
#pragma unroll
        for (int g = 0; g < 2; ++g)
#pragma unroll
            for (int j = 0; j < 4; ++j) {
                sA[g][j] += __shfl_xor(sA[g][j], 1); qA[g][j] += __shfl_xor(qA[g][j], 1);
                sA[g][j] += __shfl_xor(sA[g][j], 2); qA[g][j] += __shfl_xor(qA[g][j], 2);
                sA[g][j] += __shfl_xor(sA[g][j], 4); qA[g][j] += __shfl_xor(qA[g][j], 4);
                sA[g][j] += __shfl_xor(sA[g][j], 8); qA[g][j] += __shfl_xor(qA[g][j], 8);
            }
        if (cl == 0) {
#pragma unroll
            for (int g = 0; g < 2; ++g)
#pragma unroll
                for (int j = 0; j < 4; ++j) {
                    redA[wid][g * 16 + rbase + j] = sA[g][j];
                    redB[wid][g * 16 + rbase + j] = qA[g][j];
                }
        }
    }
    __syncthreads();
    if (t < 32) {
        float s = redA[0][t] + redA[1][t] + redA[2][t] + redA[3][t];
        float q = redB[0][t] + redB[1][t] + redB[2][t] + redB[3][t];
        float mu  = s * (1.f / 2048.f);
        float var = q * (1.f / 2048.f) - mu * mu;
        muS[t] = mu;
        rsS[t] = rsqrtf(var + 1e-5f);
    }
    __syncthreads();

    // ---- phase 4 (pass B): read fz (this block's rows), normalize, write.
    // thread t owns 8 consecutive h for all 32 rows (coalesced bf16x8 loads)
    {
        const int h0 = t * 8;
        f32x4 g0 = *(const f32x4*)&gamma[h0];
        f32x4 g1 = *(const f32x4*)&gamma[h0 + 4];
        f32x4 b0 = *(const f32x4*)&beta[h0];
        f32x4 b1 = *(const f32x4*)&beta[h0 + 4];
#pragma unroll
        for (int r = 0; r < 32; ++r) {
            float mu = muS[r], rs = rsS[r];
            bf16x8 fv = *(const bf16x8*)&fz[(row0 + r) * HH + h0];
            f32x4 oa, ob;
#pragma unroll
            for (int jj = 0; jj < 4; ++jj) {
                oa[jj] = ((float)fv[jj]     - mu) * rs * g0[jj] + b0[jj];
                ob[jj] = ((float)fv[jj + 4] - mu) * rs * g1[jj] + b1[jj];
            }
            float* po = &out[O_OUT + (row0 + r) * HH + h0];
            *(f32x4*)po       = oa;
            *(f32x4*)(po + 4) = ob;
        }
    }
}

// xbar[b][h] = sum over 128 block-partials (bf16) per batch
__global__ __launch_bounds__(256)
void xred_k(const bf16* __restrict__ xpart, float* __restrict__ xbar)
{
    int o = blockIdx.x * 256 + threadIdx.x;   // 0..8191
    int b = o >> 11, h = o & 2047;
    const bf16* p = xpart + (size_t)(b * 128) * 2048 + h;
    float acc = 0.f;
    for (int k = 0; k < 128; ++k) acc += (float)p[(size_t)k * 2048];
    xbar[o] = acc;
}

// kb/vb[b,h] = bias[h] + (1/4096) * sum_i xbar[b,i]*W[h,i]  (4-way i-split)
__global__ __launch_bounds__(256)
void kbvb_k(const float* __restrict__ xbar,
            const float* __restrict__ Wk, const float* __restrict__ bk,
            const float* __restrict__ Wv, const float* __restrict__ bv,
            float* __restrict__ kb, float* __restrict__ vb)
{
    int gt = blockIdx.x * 256 + threadIdx.x;    // 0..65535
    int out_idx = gt >> 2, part = gt & 3;
    int mat = out_idx >> 13, rem = out_idx & 8191;
    int b = rem >> 11, h = rem & 2047;
    const float* W    = mat ? Wv : Wk;
    const float* bias = mat ? bv : bk;
    const float* x    = xbar + b * HH;
    float acc = 0.f;
    const int i0 = part * 512;
    for (int i = i0; i < i0 + 512; i += 8) {
        f32x4 w0 = *(const f32x4*)&W[(size_t)h * HH + i];
        f32x4 w1 = *(const f32x4*)&W[(size_t)h * HH + i + 4];
        f32x4 x0 = *(const f32x4*)&x[i];
        f32x4 x1 = *(const f32x4*)&x[i + 4];
        acc += x0[0]*w0[0] + x0[1]*w0[1] + x0[2]*w0[2] + x0[3]*w0[3];
        acc += x1[0]*w1[0] + x1[1]*w1[1] + x1[2]*w1[2] + x1[3]*w1[3];
    }
    acc += __shfl_xor(acc, 1);
    acc += __shfl_xor(acc, 2);
    if (part == 0)
        (mat ? vb : kb)[b * HH + h] = bias[h] + acc * (1.f / 4096.f);
}

// copy mk/mv inputs (f32) to output slots (f32)
__global__ __launch_bounds__(256)
void copy_mkmv_k(const float* __restrict__ mk, const float* __restrict__ mv, float* __restrict__ out)
{
    int idx = (blockIdx.x * 256 + threadIdx.x) * 4;
    const int half = MM * HH;
    if (idx < half)
        *(f32x4*)&out[O_MK + idx] = *(const f32x4*)&mk[idx];
    else
        *(f32x4*)&out[O_MV + (idx - half)] = *(const f32x4*)&mv[idx - half];
}

// sequential argmin-scatter memory update (4 steps), single block
__global__ __launch_bounds__(256)
void scan_k(const int* __restrict__ uc_in, const int* __restrict__ ts_in,
            const float* __restrict__ kb, const float* __restrict__ vb,
            float* __restrict__ out)
{
    __shared__ int ucS[64], tsS[64];
    __shared__ int idxS, tmaxS;
    const int t = threadIdx.x;
    if (t < 64) { ucS[t] = uc_in[t]; tsS[t] = ts_in[t]; }
    __syncthreads();
    for (int b = 0; b < 4; ++b) {
        if (t < 64) {
            float bs = (float)ucS[t] + 0.1f * (float)tsS[t];
            int bi = t;
            int tm = tsS[t];
#pragma unroll
            for (int off = 1; off < 64; off <<= 1) {
                float os = __shfl_xor(bs, off);
                int   oi = __shfl_xor(bi, off);
                int   om = __shfl_xor(tm, off);
                if (os < bs || (os == bs && oi < bi)) { bs = os; bi = oi; }
                tm = max(tm, om);
            }
            if (t == 0) { idxS = bi; tmaxS = tm; }
        }
        __syncthreads();
        int idx = idxS;
        int e = t * 8;
        *(f32x4*)&out[O_MK + (size_t)idx * HH + e]     = *(const f32x4*)&kb[b * HH + e];
        *(f32x4*)&out[O_MK + (size_t)idx * HH + e + 4] = *(const f32x4*)&kb[b * HH + e + 4];
        *(f32x4*)&out[O_MV + (size_t)idx * HH + e]     = *(const f32x4*)&vb[b * HH + e];
        *(f32x4*)&out[O_MV + (size_t)idx * HH + e + 4] = *(const f32x4*)&vb[b * HH + e + 4];
        __syncthreads();
        if (t == 0) { ucS[idx] += 1; tsS[idx] = tmaxS + 1; }
        __syncthreads();
    }
    if (t < 64) {
        out[O_UC + t] = (float)ucS[t];
        out[O_TS + t] = (float)tsS[t];
    }
}

// =================================================================
extern "C" void kernel_launch(void* const* d_in, const int* in_sizes, int n_in,
                              void* d_out, int out_size, void* d_ws, size_t ws_size,
                              hipStream_t stream)
{
    const float* chs = (const float*)d_in[0];
    const float* xl  = (const float*)d_in[1];
    const float* mk  = (const float*)d_in[2];
    const float* mv  = (const float*)d_in[3];
    const float* Wq  = (const float*)d_in[4];
    const float* bq  = (const float*)d_in[5];
    const float* Wk  = (const float*)d_in[6];
    const float* bk  = (const float*)d_in[7];
    const float* Wv  = (const float*)d_in[8];
    const float* bv  = (const float*)d_in[9];
    const float* Wg1 = (const float*)d_in[10];
    const float* bg1 = (const float*)d_in[11];
    const float* Wg2 = (const float*)d_in[12];
    const float* bg2 = (const float*)d_in[13];
    const float* lng = (const float*)d_in[14];
    const float* lnb = (const float*)d_in[15];
    const int*   ucI = (const int*)d_in[16];
    const int*   tsI = (const int*)d_in[17];

    uint8_t* ws = (uint8_t*)d_ws;
    float* outp = (float*)d_out;

    bf16*  xlb  = (bf16*)(ws + WS_XLB);
    bf16*  fz   = (bf16*)(ws + WS_XLB);     // reuse: xlb dead after main GEMM
    bf16*  Cb   = (bf16*)(ws + WS_C);
    bf16*  Bmat = (bf16*)(ws + WS_BMAT);
    bf16*  WqT  = (bf16*)(ws + WS_WQT);
    bf16*  xpart= (bf16*)(ws + WS_WQT);     // reuse: WqT dead after P-GEMM (2MB < 8MB)
    bf16*  W1b  = (bf16*)(ws + WS_W1B);
    bf16*  mkP  = (bf16*)(ws + WS_MKP);
    bf16*  mvP  = (bf16*)(ws + WS_MVP);
    bf16*  q2t  = (bf16*)(ws + WS_Q2T);
    bf16*  mvT  = (bf16*)(ws + WS_MVT);
    float* Pf   = (float*)(ws + WS_PF);
    float* Q2f  = (float*)(ws + WS_Q2F);
    float* cvec = (float*)(ws + WS_CVEC);
    float* xbar = (float*)(ws + WS_XBAR);
    float* kb   = (float*)(ws + WS_KB);
    float* vb   = (float*)(ws + WS_VB);

    hipMemsetAsync(Pf, 0, (size_t)MM * HH * 4, stream);
    hipMemsetAsync(Q2f, 0, (size_t)MM * NHID * 4, stream);

    conv_xl_k<<<16384, 256, 0, stream>>>(xl, xlb);
    transpose_k<<<dim3(32, 32), 256, 0, stream>>>(Wq, WqT);
    padcpy_k<<<256, 256, 0, stream>>>(mk, mv, mkP, mvP);
    bmatfill_k<<<1088, 256, 0, stream>>>(Wg1, Bmat, W1b);
    cvec_k<<<64, 256, 0, stream>>>(bq, mk, cvec);

    // P = mkPad @ Wq  (split-K, f32 atomic)
    gemm_bt<true, false><<<dim3(1, 16, 8), 256, 0, stream>>>(mkP, HH, WqT, HH, Pf, HH, MM, 4);
    // Q2 = mvPad @ Wg1b^T
    gemm_bt<true, false><<<dim3(1, 8, 8), 256, 0, stream>>>(mvP, HH, W1b, HH, Q2f, NHID, MM, 4);
    prep2_k<<<832, 256, 0, stream>>>(Pf, Bmat, Q2f, mv, q2t, mvT);

    // main fused GEMM: [16384,2048] @ [2048,1152]  (XCD-chunked remap)
    gemm_bt<false, true><<<1152, 256, 0, stream>>>(xlb, HH, Bmat, HH, Cb, NC, ROWS, 32);

    epi_k<<<512, 256, 0, stream>>>(Cb, cvec, mvT, q2t, chs, bg1, Wg2, bg2, lng, lnb, outp, xpart, fz);

    xred_k<<<32, 256, 0, stream>>>(xpart, xbar);
    kbvb_k<<<256, 256, 0, stream>>>(xbar, Wk, bk, Wv, bv, kb, vb);
    copy_mkmv_k<<<256, 256, 0, stream>>>(mk, mv, outp);
    scan_k<<<1, 256, 0, stream>>>(ucI, tsI, kb, vb, outp);
}

// Round 15
// 334.213 us; speedup vs baseline: 1.1867x; 1.0268x over previous
//
#include <hip/hip_runtime.h>
#include <hip/hip_bf16.h>
#include <stdint.h>

typedef __bf16 bf16;
typedef __bf16 bf16x8 __attribute__((ext_vector_type(8)));
typedef __bf16 bf16x4 __attribute__((ext_vector_type(4)));
typedef float  f32x4  __attribute__((ext_vector_type(4)));

#define DI __device__ __forceinline__

// ---------------- problem sizes ----------------
constexpr int ROWS = 4 * 4096;     // B*S = 16384
constexpr int HH   = 2048;
constexpr int MM   = 64;
constexpr int NHID = 1024;
constexpr int NC   = 1152;         // 64 scores + 1024 hidden + 64 pad

// ---------------- output layout (f32 elements) ----------------
constexpr size_t O_OUT  = 0;
constexpr size_t O_GATE = (size_t)ROWS * HH;
constexpr size_t O_MK   = O_GATE + ROWS;
constexpr size_t O_MV   = O_MK + (size_t)MM * HH;
constexpr size_t O_UC   = O_MV + (size_t)MM * HH;
constexpr size_t O_TS   = O_UC + MM;

// ---------------- ws layout (bytes) ----------------
constexpr size_t WS_XLB  = 0;                                    // bf16[16384*2048]; dead after main GEMM -> fz
constexpr size_t WS_C    = WS_XLB + (size_t)ROWS * HH * 2;       // bf16[16384*1152]
constexpr size_t WS_BMAT = WS_C + (size_t)ROWS * NC * 2;         // bf16[1152*2048]
constexpr size_t WS_WQT  = WS_BMAT + (size_t)NC * HH * 2;        // bf16[2048*2048]; dead after P-GEMM -> xpart
constexpr size_t WS_W1B  = WS_WQT + (size_t)HH * HH * 2;         // bf16[1024*2048]
constexpr size_t WS_MKP  = WS_W1B + (size_t)NHID * HH * 2;       // bf16[128*2048]
constexpr size_t WS_MVP  = WS_MKP + (size_t)128 * HH * 2;        // bf16[128*2048]
constexpr size_t WS_Q2T  = WS_MVP + (size_t)128 * HH * 2;        // bf16[1024*64]
constexpr size_t WS_PF   = WS_Q2T + (size_t)NHID * MM * 2;       // f32[64*2048]
constexpr size_t WS_Q2F  = WS_PF + (size_t)MM * HH * 4;          // f32[64*1024]
constexpr size_t WS_CVEC = WS_Q2F + (size_t)MM * NHID * 4;       // f32[64]
constexpr size_t WS_XBAR = WS_CVEC + 64 * 4;                     // f32[4*2048]
constexpr size_t WS_KB   = WS_XBAR + (size_t)4 * HH * 4;         // f32[4*2048]
constexpr size_t WS_VB   = WS_KB + (size_t)4 * HH * 4;           // f32[4*2048]
constexpr size_t WS_MVT  = WS_VB + (size_t)4 * HH * 4;           // bf16[2048*64]

DI void gload16(const void* g, void* l) {
    __builtin_amdgcn_global_load_lds((__attribute__((address_space(1))) void*)g,
                                     (__attribute__((address_space(3))) void*)l,
                                     16, 0, 0);
}

DI bf16x8 cvt8(f32x4 a, f32x4 b) {
    bf16x8 v;
    v[0]=(bf16)a[0]; v[1]=(bf16)a[1]; v[2]=(bf16)a[2]; v[3]=(bf16)a[3];
    v[4]=(bf16)b[0]; v[5]=(bf16)b[1]; v[6]=(bf16)b[2]; v[7]=(bf16)b[3];
    return v;
}

DI float wave_sum(float v) {
#pragma unroll
    for (int off = 32; off; off >>= 1) v += __shfl_xor(v, off);
    return v;
}

// =================================================================
// GEMM: C[M,N] = A[M,K] @ Bt[N,K]^T   (128x128 tile, BK=64, bf16 in)
// LDS XOR-swizzle + XCD-chunked remap (verified rounds 3-14)
// =================================================================
template <bool SPLITK, bool REMAP>
__global__ __launch_bounds__(256)
void gemm_bt(const bf16* __restrict__ A, int lda,
             const bf16* __restrict__ Bt, int ldb,
             void* __restrict__ Cv, int ldc,
             int Mmax, int kit)
{
    __shared__ __align__(16) bf16 As[128 * 64];
    __shared__ __align__(16) bf16 Bs[128 * 64];
    const int tid  = threadIdx.x;
    const int wid  = tid >> 6, lane = tid & 63;
    int bx, by;
    if (REMAP) {                      // grid = 1152 linear, 9 n-tiles, 128 m-tiles
        int bid = blockIdx.x;
        int xcd = bid & 7, loc = bid >> 3;   // 144 tiles per XCD
        bx = xcd * 16 + loc / 9;
        by = loc % 9;
    } else { bx = blockIdx.x; by = blockIdx.y; }
    const int m0   = bx * 128, n0 = by * 128;
    const int wr   = wid >> 1, wc = wid & 1;
    const int kt0  = blockIdx.z * kit;
    const int srow  = lane >> 3;
    const int sslot = (lane & 7) ^ srow;

    f32x4 acc[4][4] = {};

    for (int kt = kt0; kt < kt0 + kit; ++kt) {
        const bf16* Ak = A + (size_t)kt * 64;
        const bf16* Bk = Bt + (size_t)kt * 64;
#pragma unroll
        for (int c = 0; c < 4; ++c) {
            int ch  = wid * 4 + c;
            int row = ch * 8 + srow;
            gload16(Ak + (size_t)(m0 + row) * lda + sslot * 8, As + ch * 512);
        }
#pragma unroll
        for (int c = 0; c < 4; ++c) {
            int ch  = wid * 4 + c;
            int row = ch * 8 + srow;
            gload16(Bk + (size_t)(n0 + row) * ldb + sslot * 8, Bs + ch * 512);
        }
        __syncthreads();
#pragma unroll
        for (int ks = 0; ks < 2; ++ks) {
            bf16x8 av[4], bv[4];
#pragma unroll
            for (int mi = 0; mi < 4; ++mi) {
                int r = wr * 64 + mi * 16 + (lane & 15);
                int slot = ((ks * 4 + (lane >> 4)) ^ (r & 7)) * 8;
                av[mi] = *(const bf16x8*)&As[r * 64 + slot];
            }
#pragma unroll
            for (int ni = 0; ni < 4; ++ni) {
                int r = wc * 64 + ni * 16 + (lane & 15);
                int slot = ((ks * 4 + (lane >> 4)) ^ (r & 7)) * 8;
                bv[ni] = *(const bf16x8*)&Bs[r * 64 + slot];
            }
#pragma unroll
            for (int mi = 0; mi < 4; ++mi)
#pragma unroll
                for (int ni = 0; ni < 4; ++ni)
                    acc[mi][ni] = __builtin_amdgcn_mfma_f32_16x16x32_bf16(
                        av[mi], bv[ni], acc[mi][ni], 0, 0, 0);
        }
        __syncthreads();
    }

#pragma unroll
    for (int mi = 0; mi < 4; ++mi) {
#pragma unroll
        for (int ni = 0; ni < 4; ++ni) {
            int col = n0 + wc * 64 + ni * 16 + (lane & 15);
#pragma unroll
            for (int j = 0; j < 4; ++j) {
                int row = m0 + wr * 64 + mi * 16 + (lane >> 4) * 4 + j;
                if (row < Mmax) {
                    if (SPLITK)
                        atomicAdd((float*)Cv + (size_t)row * ldc + col, acc[mi][ni][j]);
                    else
                        ((bf16*)Cv)[(size_t)row * ldc + col] = (bf16)acc[mi][ni][j];
                }
            }
        }
    }
}

// xl (f32) -> xlb (bf16)
__global__ __launch_bounds__(256)
void conv_xl_k(const float* __restrict__ xl, bf16* __restrict__ xlb)
{
    size_t idx = ((size_t)blockIdx.x * 256 + threadIdx.x) * 8;
    f32x4 a = *(const f32x4*)&xl[idx];
    f32x4 b = *(const f32x4*)&xl[idx + 4];
    *(bf16x8*)&xlb[idx] = cvt8(a, b);
}

// =================================================================
// Merged prep: transpose Wq (blocks 0..1023), padcpy mk/mv (1024..1279),
// bmatfill Wg1 (1280..2367), cvec (2368..2431). All independent.
// =================================================================
__global__ __launch_bounds__(256)
void prep1_k(const float* __restrict__ Wq, bf16* __restrict__ WqT,
             const float* __restrict__ mk, const float* __restrict__ mv,
             bf16* __restrict__ mkP, bf16* __restrict__ mvP,
             const float* __restrict__ Wg1, bf16* __restrict__ Bmat, bf16* __restrict__ W1b,
             const float* __restrict__ bq, float* __restrict__ cvec)
{
    __shared__ float T[64][72];
    __shared__ float wS[4];
    const int bid = blockIdx.x;
    const int t = threadIdx.x;

    if (bid < 1024) {
        // ---- transpose: Wq f32 [o][i] -> WqT bf16 [i][o]
        const int bx = bid & 31, byy = bid >> 5;
        const int o0 = byy * 64, i0 = bx * 64;
        const int r = t >> 3, c8 = (t & 7) * 8;
#pragma unroll
        for (int rep = 0; rep < 2; ++rep) {
            int row = r + rep * 32;
            *(f32x4*)&T[row][c8]     = *(const f32x4*)&Wq[(size_t)(o0 + row) * HH + i0 + c8];
            *(f32x4*)&T[row][c8 + 4] = *(const f32x4*)&Wq[(size_t)(o0 + row) * HH + i0 + c8 + 4];
        }
        __syncthreads();
#pragma unroll
        for (int rep = 0; rep < 2; ++rep) {
            int irow = r + rep * 32;
            bf16x8 v;
#pragma unroll
            for (int jj = 0; jj < 8; ++jj) v[jj] = (bf16)T[c8 + jj][irow];
            *(bf16x8*)&WqT[(size_t)(i0 + irow) * HH + o0 + c8] = v;
        }
    } else if (bid < 1280) {
        // ---- padcpy: mk/mv f32 -> mkP/mvP bf16 [128,2048] zero-padded
        int idx = ((bid - 1024) * 256 + t) * 8;
        const int half = 128 * HH;
        const float* s; bf16* d; int i;
        if (idx < half) { i = idx; d = mkP; s = mk; }
        else            { i = idx - half; d = mvP; s = mv; }
        bf16x8 v = {};
        if (i < MM * HH) {
            f32x4 a = *(const f32x4*)&s[i];
            f32x4 b = *(const f32x4*)&s[i + 4];
            v = cvt8(a, b);
        }
        *(bf16x8*)&d[i] = v;
    } else if (bid < 2368) {
        // ---- bmatfill: Bmat rows 64..1151 <- Wg1[:, :2048]; W1b <- Wg1[:, 2048:]
        int row = 64 + (bid - 1280);
        int c8  = t * 8;
        int j   = row - 64;
        bf16x8 v = {};
        if (j < NHID) {
            f32x4 a = *(const f32x4*)&Wg1[(size_t)j * 4096 + c8];
            f32x4 b = *(const f32x4*)&Wg1[(size_t)j * 4096 + c8 + 4];
            v = cvt8(a, b);
            f32x4 c = *(const f32x4*)&Wg1[(size_t)j * 4096 + 2048 + c8];
            f32x4 d = *(const f32x4*)&Wg1[(size_t)j * 4096 + 2048 + c8 + 4];
            *(bf16x8*)&W1b[(size_t)j * HH + c8] = cvt8(c, d);
        }
        *(bf16x8*)&Bmat[(size_t)row * HH + c8] = v;
    } else {
        // ---- cvec[m] = sum_o bq[o]*mk[m,o]
        const int m = bid - 2368, wid = t >> 6, lane = t & 63;
        const int o0 = t * 8;
        f32x4 b0 = *(const f32x4*)&bq[o0];
        f32x4 b1 = *(const f32x4*)&bq[o0 + 4];
        f32x4 k0 = *(const f32x4*)&mk[(size_t)m * HH + o0];
        f32x4 k1 = *(const f32x4*)&mk[(size_t)m * HH + o0 + 4];
        float acc = b0[0]*k0[0] + b0[1]*k0[1] + b0[2]*k0[2] + b0[3]*k0[3]
                  + b1[0]*k1[0] + b1[1]*k1[1] + b1[2]*k1[2] + b1[3]*k1[3];
        acc = wave_sum(acc);
        if (lane == 0) wS[wid] = acc;
        __syncthreads();
        if (t == 0) cvec[m] = wS[0] + wS[1] + wS[2] + wS[3];
    }
}

// merged: Pf->Bmat rows 0..63 ; Q2f -> q2t (transposed bf16) ; mv -> mvT
__global__ __launch_bounds__(256)
void prep2_k(const float* __restrict__ Pf, bf16* __restrict__ Bmat,
             const float* __restrict__ Q2f, const float* __restrict__ mv,
             bf16* __restrict__ q2t, bf16* __restrict__ mvT)
{
    int gid = blockIdx.x * 256 + threadIdx.x;
    if (gid < 16384) {                       // Pf -> Bmat (x8 vectorized)
        int idx = gid * 8;
        f32x4 a = *(const f32x4*)&Pf[idx];
        f32x4 b = *(const f32x4*)&Pf[idx + 4];
        *(bf16x8*)&Bmat[idx] = cvt8(a, b);
    } else if (gid < 16384 + NHID * MM) {    // q2t[j][m] = Q2f[m][j]
        int idx = gid - 16384;
        int j = idx >> 6, m = idx & 63;
        q2t[idx] = (bf16)Q2f[(size_t)m * NHID + j];
    } else {                                 // mvT[h][m] = mv[m][h]
        int i = gid - 16384 - NHID * MM;
        int h = i >> 6, m = i & 63;
        mvT[i] = (bf16)mv[(size_t)m * HH + h];
    }
}

// =================================================================
// MFMA epilogue v8 (r14-verified) + T5 setprio around MFMA clusters.
// 32 rows/block, 512 blocks, 256 threads.
// Pass A: MFMA + fuse -> fz (bf16) + LN stats + xpart.
// Pass B: read fz linearly, normalize, write out.
// =================================================================
__global__ __launch_bounds__(256)
void epi_k(const bf16* __restrict__ Cb, const float* __restrict__ cvec,
           const bf16* __restrict__ mvT, const bf16* __restrict__ q2t,
           const float* __restrict__ chs,
           const float* __restrict__ bg1, const float* __restrict__ w2,
           const float* __restrict__ bg2,
           const float* __restrict__ gamma, const float* __restrict__ beta,
           float* __restrict__ out, bf16* __restrict__ xpart,
           bf16* __restrict__ fz)
{
    __shared__ __align__(16) bf16 attnB[32 * 64];
    __shared__ float redA[4][32], redB[4][32];
    __shared__ float gS[32], muS[32], rsS[32];
    const int t = threadIdx.x, wid = t >> 6, lane = t & 63;
    const size_t row0 = (size_t)blockIdx.x * 32;
    const int cl = lane & 15;
    const int rbase = (lane >> 4) * 4;

    // ---- phase 1: softmax; wave w -> rows 8w..8w+7
    {
        float cv = cvec[lane];
#pragma unroll
        for (int rr = 0; rr < 8; ++rr) {
            int r = wid * 8 + rr;
            float s = (float)Cb[(row0 + r) * NC + lane] + cv;
            float mx = s;
#pragma unroll
            for (int off = 32; off; off >>= 1) mx = fmaxf(mx, __shfl_xor(mx, off));
            float e = expf(s - mx);
            float sum = e;
#pragma unroll
            for (int off = 32; off; off >>= 1) sum += __shfl_xor(sum, off);
            attnB[r * 64 + lane] = (bf16)(e / sum);
        }
    }
    __syncthreads();

    // A-fragments for both 16-row groups (verified layout)
    bf16x8 av00 = *(const bf16x8*)&attnB[(cl)      * 64 +  0 + (lane >> 4) * 8];
    bf16x8 av01 = *(const bf16x8*)&attnB[(cl)      * 64 + 32 + (lane >> 4) * 8];
    bf16x8 av10 = *(const bf16x8*)&attnB[(16 + cl) * 64 +  0 + (lane >> 4) * 8];
    bf16x8 av11 = *(const bf16x8*)&attnB[(16 + cl) * 64 + 32 + (lane >> 4) * 8];

    // ---- phase 2: gate — one B-load feeds both groups
    {
        float gp[2][4] = {};
#pragma unroll
        for (int nt = 0; nt < 16; ++nt) {
            int ct = wid * 256 + nt * 16 + cl;
            bf16x8 bv0 = *(const bf16x8*)&q2t[(size_t)ct * 64 +  0 + (lane >> 4) * 8];
            bf16x8 bv1 = *(const bf16x8*)&q2t[(size_t)ct * 64 + 32 + (lane >> 4) * 8];
            float b1 = bg1[ct], wv = w2[ct];
            f32x4 a0 = {}, a1 = {};
            __builtin_amdgcn_s_setprio(1);
            a0 = __builtin_amdgcn_mfma_f32_16x16x32_bf16(av00, bv0, a0, 0, 0, 0);
            a0 = __builtin_amdgcn_mfma_f32_16x16x32_bf16(av01, bv1, a0, 0, 0, 0);
            a1 = __builtin_amdgcn_mfma_f32_16x16x32_bf16(av10, bv0, a1, 0, 0, 0);
            a1 = __builtin_amdgcn_mfma_f32_16x16x32_bf16(av11, bv1, a1, 0, 0, 0);
            __builtin_amdgcn_s_setprio(0);
#pragma unroll
            for (int j = 0; j < 4; ++j) {
                float c0 = (float)Cb[(row0 + rbase + j) * NC + 64 + ct];
                float c1 = (float)Cb[(row0 + 16 + rbase + j) * NC + 64 + ct];
                gp[0][j] += fmaxf(c0 + b1 + a0[j], 0.f) * wv;
                gp[1][j] += fmaxf(c1 + b1 + a1[j], 0.f) * wv;
            }
        }
#pragma unroll
        for (int g = 0; g < 2; ++g)
#pragma unroll
            for (int j = 0; j < 4; ++j) {
                gp[g][j] += __shfl_xor(gp[g][j], 1);
                gp[g][j] += __shfl_xor(gp[g][j], 2);
                gp[g][j] += __shfl_xor(gp[g][j], 4);
                gp[g][j] += __shfl_xor(gp[g][j], 8);
            }
        if (cl == 0) {
#pragma unroll
            for (int g = 0; g < 2; ++g)
#pragma unroll
                for (int j = 0; j < 4; ++j) redA[wid][g * 16 + rbase + j] = gp[g][j];
        }
    }
    __syncthreads();
    if (t < 32) {
        float g = redA[0][t] + redA[1][t] + redA[2][t] + redA[3][t];
        g = 1.f / (1.f + expf(-(g + bg2[0])));
        gS[t] = g;
        out[O_GATE + row0 + t] = g;
    }
    __syncthreads();

    float gR[2][4], omR[2][4];
#pragma unroll
    for (int g = 0; g < 2; ++g)
#pragma unroll
        for (int j = 0; j < 4; ++j) { gR[g][j] = gS[g * 16 + rbase + j]; omR[g][j] = 1.f - gR[g][j]; }

    // ---- phase 3 (pass A): retrieved MFMA + fuse -> fz store + LN stats + xpart
    {
        float sA[2][4] = {}, qA[2][4] = {};
        for (int nt = 0; nt < 32; ++nt) {
            int ct = wid * 512 + nt * 16 + cl;
            bf16x8 bv0 = *(const bf16x8*)&mvT[(size_t)ct * 64 +  0 + (lane >> 4) * 8];
            bf16x8 bv1 = *(const bf16x8*)&mvT[(size_t)ct * 64 + 32 + (lane >> 4) * 8];
            f32x4 a0 = {}, a1 = {};
            __builtin_amdgcn_s_setprio(1);
            a0 = __builtin_amdgcn_mfma_f32_16x16x32_bf16(av00, bv0, a0, 0, 0, 0);
            a0 = __builtin_amdgcn_mfma_f32_16x16x32_bf16(av01, bv1, a0, 0, 0, 0);
            a1 = __builtin_amdgcn_mfma_f32_16x16x32_bf16(av10, bv0, a1, 0, 0, 0);
            a1 = __builtin_amdgcn_mfma_f32_16x16x32_bf16(av11, bv1, a1, 0, 0, 0);
            __builtin_amdgcn_s_setprio(0);
            float xc = 0.f;
#pragma unroll
            for (int j = 0; j < 4; ++j) {
                float x0 = chs[(row0 + rbase + j) * HH + ct];
                float x1 = chs[(row0 + 16 + rbase + j) * HH + ct];
                xc += x0 + x1;
                float f0 = omR[0][j] * x0 + gR[0][j] * a0[j];
                float f1 = omR[1][j] * x1 + gR[1][j] * a1[j];
                fz[(row0 + rbase + j) * HH + ct]      = (bf16)f0;
                fz[(row0 + 16 + rbase + j) * HH + ct] = (bf16)f1;
                sA[0][j] += f0; qA[0][j] += f0 * f0;
                sA[1][j] += f1; qA[1][j] += f1 * f1;
            }
            xc += __shfl_xor(xc, 16);
            xc += __shfl_xor(xc, 32);
            if (lane < 16) xpart[(size_t)blockIdx.x * 2048 + ct] = (bf16)xc;
        }
#pragma unroll
        for (int g = 0; g < 2; ++g)
#pragma unroll
            for (int j = 0; j < 4; ++j) {
                sA[g][j] += __shfl_xor(sA[g][j], 1); qA[g][j] += __shfl_xor(qA[g][j], 1);
                sA[g][j] += __shfl_xor(sA[g][j], 2); qA[g][j] += __shfl_xor(qA[g][j], 2);
                sA[g][j] += __shfl_xor(sA[g][j], 4); qA[g][j] += __shfl_xor(qA[g][j], 4);
                sA[g][j] += __shfl_xor(sA[g][j], 8); qA[g][j] += __shfl_xor(qA[g][j], 8);
            }
        if (cl == 0) {
#pragma unroll
            for (int g = 0; g < 2; ++g)
#pragma unroll
                for (int j = 0; j < 4; ++j) {
                    redA[wid][g * 16 + rbase + j] = sA[g][j];
                    redB[wid][g * 16 + rbase + j] = qA[g][j];
                }
        }
    }
    __syncthreads();
    if (t < 32) {
        float s = redA[0][t] + redA[1][t] + redA[2][t] + redA[3][t];
        float q = redB[0][t] + redB[1][t] + redB[2][t] + redB[3][t];
        float mu  = s * (1.f / 2048.f);
        float var = q * (1.f / 2048.f) - mu * mu;
        muS[t] = mu;
        rsS[t] = rsqrtf(var + 1e-5f);
    }
    __syncthreads();

    // ---- phase 4 (pass B): read fz (this block's rows), normalize, write.
    {
        const int h0 = t * 8;
        f32x4 g0 = *(const f32x4*)&gamma[h0];
        f32x4 g1 = *(const f32x4*)&gamma[h0 + 4];
        f32x4 b0 = *(const f32x4*)&beta[h0];
        f32x4 b1 = *(const f32x4*)&beta[h0 + 4];
#pragma unroll
        for (int r = 0; r < 32; ++r) {
            float mu = muS[r], rs = rsS[r];
            bf16x8 fv = *(const bf16x8*)&fz[(row0 + r) * HH + h0];
            f32x4 oa, ob;
#pragma unroll
            for (int jj = 0; jj < 4; ++jj) {
                oa[jj] = ((float)fv[jj]     - mu) * rs * g0[jj] + b0[jj];
                ob[jj] = ((float)fv[jj + 4] - mu) * rs * g1[jj] + b1[jj];
            }
            float* po = &out[O_OUT + (row0 + r) * HH + h0];
            *(f32x4*)po       = oa;
            *(f32x4*)(po + 4) = ob;
        }
    }
}

// xbar[b][h] = sum over 128 block-partials (bf16) per batch
__global__ __launch_bounds__(256)
void xred_k(const bf16* __restrict__ xpart, float* __restrict__ xbar)
{
    int o = blockIdx.x * 256 + threadIdx.x;   // 0..8191
    int b = o >> 11, h = o & 2047;
    const bf16* p = xpart + (size_t)(b * 128) * 2048 + h;
    float acc = 0.f;
    for (int k = 0; k < 128; ++k) acc += (float)p[(size_t)k * 2048];
    xbar[o] = acc;
}

// kb/vb[b,h] = bias[h] + (1/4096) * sum_i xbar[b,i]*W[h,i]  (4-way i-split)
__global__ __launch_bounds__(256)
void kbvb_k(const float* __restrict__ xbar,
            const float* __restrict__ Wk, const float* __restrict__ bk,
            const float* __restrict__ Wv, const float* __restrict__ bv,
            float* __restrict__ kb, float* __restrict__ vb)
{
    int gt = blockIdx.x * 256 + threadIdx.x;    // 0..65535
    int out_idx = gt >> 2, part = gt & 3;
    int mat = out_idx >> 13, rem = out_idx & 8191;
    int b = rem >> 11, h = rem & 2047;
    const float* W    = mat ? Wv : Wk;
    const float* bias = mat ? bv : bk;
    const float* x    = xbar + b * HH;
    float acc = 0.f;
    const int i0 = part * 512;
    for (int i = i0; i < i0 + 512; i += 8) {
        f32x4 w0 = *(const f32x4*)&W[(size_t)h * HH + i];
        f32x4 w1 = *(const f32x4*)&W[(size_t)h * HH + i + 4];
        f32x4 x0 = *(const f32x4*)&x[i];
        f32x4 x1 = *(const f32x4*)&x[i + 4];
        acc += x0[0]*w0[0] + x0[1]*w0[1] + x0[2]*w0[2] + x0[3]*w0[3];
        acc += x1[0]*w1[0] + x1[1]*w1[1] + x1[2]*w1[2] + x1[3]*w1[3];
    }
    acc += __shfl_xor(acc, 1);
    acc += __shfl_xor(acc, 2);
    if (part == 0)
        (mat ? vb : kb)[b * HH + h] = bias[h] + acc * (1.f / 4096.f);
}

// copy mk/mv inputs (f32) to output slots (f32)
__global__ __launch_bounds__(256)
void copy_mkmv_k(const float* __restrict__ mk, const float* __restrict__ mv, float* __restrict__ out)
{
    int idx = (blockIdx.x * 256 + threadIdx.x) * 4;
    const int half = MM * HH;
    if (idx < half)
        *(f32x4*)&out[O_MK + idx] = *(const f32x4*)&mk[idx];
    else
        *(f32x4*)&out[O_MV + (idx - half)] = *(const f32x4*)&mv[idx - half];
}

// sequential argmin-scatter memory update (4 steps), single block
__global__ __launch_bounds__(256)
void scan_k(const int* __restrict__ uc_in, const int* __restrict__ ts_in,
            const float* __restrict__ kb, const float* __restrict__ vb,
            float* __restrict__ out)
{
    __shared__ int ucS[64], tsS[64];
    __shared__ int idxS, tmaxS;
    const int t = threadIdx.x;
    if (t < 64) { ucS[t] = uc_in[t]; tsS[t] = ts_in[t]; }
    __syncthreads();
    for (int b = 0; b < 4; ++b) {
        if (t < 64) {
            float bs = (float)ucS[t] + 0.1f * (float)tsS[t];
            int bi = t;
            int tm = tsS[t];
#pragma unroll
            for (int off = 1; off < 64; off <<= 1) {
                float os = __shfl_xor(bs, off);
                int   oi = __shfl_xor(bi, off);
                int   om = __shfl_xor(tm, off);
                if (os < bs || (os == bs && oi < bi)) { bs = os; bi = oi; }
                tm = max(tm, om);
            }
            if (t == 0) { idxS = bi; tmaxS = tm; }
        }
        __syncthreads();
        int idx = idxS;
        int e = t * 8;
        *(f32x4*)&out[O_MK + (size_t)idx * HH + e]     = *(const f32x4*)&kb[b * HH + e];
        *(f32x4*)&out[O_MK + (size_t)idx * HH + e + 4] = *(const f32x4*)&kb[b * HH + e + 4];
        *(f32x4*)&out[O_MV + (size_t)idx * HH + e]     = *(const f32x4*)&vb[b * HH + e];
        *(f32x4*)&out[O_MV + (size_t)idx * HH + e + 4] = *(const f32x4*)&vb[b * HH + e + 4];
        __syncthreads();
        if (t == 0) { ucS[idx] += 1; tsS[idx] = tmaxS + 1; }
        __syncthreads();
    }
    if (t < 64) {
        out[O_UC + t] = (float)ucS[t];
        out[O_TS + t] = (float)tsS[t];
    }
}

// =================================================================
extern "C" void kernel_launch(void* const* d_in, const int* in_sizes, int n_in,
                              void* d_out, int out_size, void* d_ws, size_t ws_size,
                              hipStream_t stream)
{
    const float* chs = (const float*)d_in[0];
    const float* xl  = (const float*)d_in[1];
    const float* mk  = (const float*)d_in[2];
    const float* mv  = (const float*)d_in[3];
    const float* Wq  = (const float*)d_in[4];
    const float* bq  = (const float*)d_in[5];
    const float* Wk  = (const float*)d_in[6];
    const float* bk  = (const float*)d_in[7];
    const float* Wv  = (const float*)d_in[8];
    const float* bv  = (const float*)d_in[9];
    const float* Wg1 = (const float*)d_in[10];
    const float* bg1 = (const float*)d_in[11];
    const float* Wg2 = (const float*)d_in[12];
    const float* bg2 = (const float*)d_in[13];
    const float* lng = (const float*)d_in[14];
    const float* lnb = (const float*)d_in[15];
    const int*   ucI = (const int*)d_in[16];
    const int*   tsI = (const int*)d_in[17];

    uint8_t* ws = (uint8_t*)d_ws;
    float* outp = (float*)d_out;

    bf16*  xlb  = (bf16*)(ws + WS_XLB);
    bf16*  fz   = (bf16*)(ws + WS_XLB);     // reuse: xlb dead after main GEMM
    bf16*  Cb   = (bf16*)(ws + WS_C);
    bf16*  Bmat = (bf16*)(ws + WS_BMAT);
    bf16*  WqT  = (bf16*)(ws + WS_WQT);
    bf16*  xpart= (bf16*)(ws + WS_WQT);     // reuse: WqT dead after P-GEMM
    bf16*  W1b  = (bf16*)(ws + WS_W1B);
    bf16*  mkP  = (bf16*)(ws + WS_MKP);
    bf16*  mvP  = (bf16*)(ws + WS_MVP);
    bf16*  q2t  = (bf16*)(ws + WS_Q2T);
    bf16*  mvT  = (bf16*)(ws + WS_MVT);
    float* Pf   = (float*)(ws + WS_PF);
    float* Q2f  = (float*)(ws + WS_Q2F);
    float* cvec = (float*)(ws + WS_CVEC);
    float* xbar = (float*)(ws + WS_XBAR);
    float* kb   = (float*)(ws + WS_KB);
    float* vb   = (float*)(ws + WS_VB);

    hipMemsetAsync(Pf, 0, (size_t)MM * HH * 4, stream);
    hipMemsetAsync(Q2f, 0, (size_t)MM * NHID * 4, stream);

    conv_xl_k<<<16384, 256, 0, stream>>>(xl, xlb);
    prep1_k<<<2432, 256, 0, stream>>>(Wq, WqT, mk, mv, mkP, mvP, Wg1, Bmat, W1b, bq, cvec);

    // P = mkPad @ Wq  (split-K, f32 atomic)
    gemm_bt<true, false><<<dim3(1, 16, 8), 256, 0, stream>>>(mkP, HH, WqT, HH, Pf, HH, MM, 4);
    // Q2 = mvPad @ Wg1b^T
    gemm_bt<true, false><<<dim3(1, 8, 8), 256, 0, stream>>>(mvP, HH, W1b, HH, Q2f, NHID, MM, 4);
    prep2_k<<<832, 256, 0, stream>>>(Pf, Bmat, Q2f, mv, q2t, mvT);

    // main fused GEMM: [16384,2048] @ [2048,1152]  (XCD-chunked remap)
    gemm_bt<false, true><<<1152, 256, 0, stream>>>(xlb, HH, Bmat, HH, Cb, NC, ROWS, 32);

    epi_k<<<512, 256, 0, stream>>>(Cb, cvec, mvT, q2t, chs, bg1, Wg2, bg2, lng, lnb, outp, xpart, fz);

    xred_k<<<32, 256, 0, stream>>>(xpart, xbar);
    kbvb_k<<<256, 256, 0, stream>>>(xbar, Wk, bk, Wv, bv, kb, vb);
    copy_mkmv_k<<<256, 256, 0, stream>>>(mk, mv, outp);
    scan_k<<<1, 256, 0, stream>>>(ucI, tsI, kb, vb, outp);
}

// Round 16
// 327.988 us; speedup vs baseline: 1.2092x; 1.0190x over previous
//
#include <hip/hip_runtime.h>
#include <hip/hip_bf16.h>
#include <stdint.h>

typedef __bf16 bf16;
typedef __bf16 bf16x8 __attribute__((ext_vector_type(8)));
typedef __bf16 bf16x4 __attribute__((ext_vector_type(4)));
typedef float  f32x4  __attribute__((ext_vector_type(4)));

#define DI __device__ __forceinline__

// ---------------- problem sizes ----------------
constexpr int ROWS = 4 * 4096;     // B*S = 16384
constexpr int HH   = 2048;
constexpr int MM   = 64;
constexpr int NHID = 1024;
constexpr int NC   = 1152;         // 64 scores + 1024 hidden + 64 pad

// ---------------- output layout (f32 elements) ----------------
constexpr size_t O_OUT  = 0;
constexpr size_t O_GATE = (size_t)ROWS * HH;
constexpr size_t O_MK   = O_GATE + ROWS;
constexpr size_t O_MV   = O_MK + (size_t)MM * HH;
constexpr size_t O_UC   = O_MV + (size_t)MM * HH;
constexpr size_t O_TS   = O_UC + MM;

// ---------------- ws layout (bytes) ----------------
constexpr size_t WS_XLB  = 0;                                    // bf16[16384*2048]; dead after main GEMM -> fz
constexpr size_t WS_C    = WS_XLB + (size_t)ROWS * HH * 2;       // bf16[16384*1152]
constexpr size_t WS_BMAT = WS_C + (size_t)ROWS * NC * 2;         // bf16[1152*2048]
constexpr size_t WS_WQT  = WS_BMAT + (size_t)NC * HH * 2;        // bf16[2048*2048]; dead after P-GEMM -> xpart
constexpr size_t WS_W1B  = WS_WQT + (size_t)HH * HH * 2;         // bf16[1024*2048]
constexpr size_t WS_MKP  = WS_W1B + (size_t)NHID * HH * 2;       // bf16[128*2048]
constexpr size_t WS_MVP  = WS_MKP + (size_t)128 * HH * 2;        // bf16[128*2048]
constexpr size_t WS_Q2T  = WS_MVP + (size_t)128 * HH * 2;        // bf16[1024*64]
constexpr size_t WS_PF   = WS_Q2T + (size_t)NHID * MM * 2;       // f32[64*2048]
constexpr size_t WS_Q2F  = WS_PF + (size_t)MM * HH * 4;          // f32[64*1024]
constexpr size_t WS_CVEC = WS_Q2F + (size_t)MM * NHID * 4;       // f32[64]
constexpr size_t WS_XBAR = WS_CVEC + 64 * 4;                     // f32[4*2048]
constexpr size_t WS_KB   = WS_XBAR + (size_t)4 * HH * 4;         // f32[4*2048]
constexpr size_t WS_VB   = WS_KB + (size_t)4 * HH * 4;           // f32[4*2048]
constexpr size_t WS_MVT  = WS_VB + (size_t)4 * HH * 4;           // bf16[2048*64]
constexpr size_t WS_STAT = WS_MVT + (size_t)HH * MM * 2;         // f32[2*16384] (mu, rs)

DI void gload16(const void* g, void* l) {
    __builtin_amdgcn_global_load_lds((__attribute__((address_space(1))) void*)g,
                                     (__attribute__((address_space(3))) void*)l,
                                     16, 0, 0);
}

DI bf16x8 cvt8(f32x4 a, f32x4 b) {
    bf16x8 v;
    v[0]=(bf16)a[0]; v[1]=(bf16)a[1]; v[2]=(bf16)a[2]; v[3]=(bf16)a[3];
    v[4]=(bf16)b[0]; v[5]=(bf16)b[1]; v[6]=(bf16)b[2]; v[7]=(bf16)b[3];
    return v;
}

DI float wave_sum(float v) {
#pragma unroll
    for (int off = 32; off; off >>= 1) v += __shfl_xor(v, off);
    return v;
}

// =================================================================
// GEMM: C[M,N] = A[M,K] @ Bt[N,K]^T   (128x128 tile, BK=64, bf16 in)
// LDS XOR-swizzle + XCD-chunked remap (verified rounds 3-15)
// =================================================================
template <bool SPLITK, bool REMAP>
__global__ __launch_bounds__(256)
void gemm_bt(const bf16* __restrict__ A, int lda,
             const bf16* __restrict__ Bt, int ldb,
             void* __restrict__ Cv, int ldc,
             int Mmax, int kit)
{
    __shared__ __align__(16) bf16 As[128 * 64];
    __shared__ __align__(16) bf16 Bs[128 * 64];
    const int tid  = threadIdx.x;
    const int wid  = tid >> 6, lane = tid & 63;
    int bx, by;
    if (REMAP) {                      // grid = 1152 linear, 9 n-tiles, 128 m-tiles
        int bid = blockIdx.x;
        int xcd = bid & 7, loc = bid >> 3;   // 144 tiles per XCD
        bx = xcd * 16 + loc / 9;
        by = loc % 9;
    } else { bx = blockIdx.x; by = blockIdx.y; }
    const int m0   = bx * 128, n0 = by * 128;
    const int wr   = wid >> 1, wc = wid & 1;
    const int kt0  = blockIdx.z * kit;
    const int srow  = lane >> 3;
    const int sslot = (lane & 7) ^ srow;

    f32x4 acc[4][4] = {};

    for (int kt = kt0; kt < kt0 + kit; ++kt) {
        const bf16* Ak = A + (size_t)kt * 64;
        const bf16* Bk = Bt + (size_t)kt * 64;
#pragma unroll
        for (int c = 0; c < 4; ++c) {
            int ch  = wid * 4 + c;
            int row = ch * 8 + srow;
            gload16(Ak + (size_t)(m0 + row) * lda + sslot * 8, As + ch * 512);
        }
#pragma unroll
        for (int c = 0; c < 4; ++c) {
            int ch  = wid * 4 + c;
            int row = ch * 8 + srow;
            gload16(Bk + (size_t)(n0 + row) * ldb + sslot * 8, Bs + ch * 512);
        }
        __syncthreads();
#pragma unroll
        for (int ks = 0; ks < 2; ++ks) {
            bf16x8 av[4], bv[4];
#pragma unroll
            for (int mi = 0; mi < 4; ++mi) {
                int r = wr * 64 + mi * 16 + (lane & 15);
                int slot = ((ks * 4 + (lane >> 4)) ^ (r & 7)) * 8;
                av[mi] = *(const bf16x8*)&As[r * 64 + slot];
            }
#pragma unroll
            for (int ni = 0; ni < 4; ++ni) {
                int r = wc * 64 + ni * 16 + (lane & 15);
                int slot = ((ks * 4 + (lane >> 4)) ^ (r & 7)) * 8;
                bv[ni] = *(const bf16x8*)&Bs[r * 64 + slot];
            }
#pragma unroll
            for (int mi = 0; mi < 4; ++mi)
#pragma unroll
                for (int ni = 0; ni < 4; ++ni)
                    acc[mi][ni] = __builtin_amdgcn_mfma_f32_16x16x32_bf16(
                        av[mi], bv[ni], acc[mi][ni], 0, 0, 0);
        }
        __syncthreads();
    }

#pragma unroll
    for (int mi = 0; mi < 4; ++mi) {
#pragma unroll
        for (int ni = 0; ni < 4; ++ni) {
            int col = n0 + wc * 64 + ni * 16 + (lane & 15);
#pragma unroll
            for (int j = 0; j < 4; ++j) {
                int row = m0 + wr * 64 + mi * 16 + (lane >> 4) * 4 + j;
                if (row < Mmax) {
                    if (SPLITK)
                        atomicAdd((float*)Cv + (size_t)row * ldc + col, acc[mi][ni][j]);
                    else
                        ((bf16*)Cv)[(size_t)row * ldc + col] = (bf16)acc[mi][ni][j];
                }
            }
        }
    }
}

// xl (f32) -> xlb (bf16)
__global__ __launch_bounds__(256)
void conv_xl_k(const float* __restrict__ xl, bf16* __restrict__ xlb)
{
    size_t idx = ((size_t)blockIdx.x * 256 + threadIdx.x) * 8;
    f32x4 a = *(const f32x4*)&xl[idx];
    f32x4 b = *(const f32x4*)&xl[idx + 4];
    *(bf16x8*)&xlb[idx] = cvt8(a, b);
}

// =================================================================
// Merged prep: transpose Wq (blocks 0..1023), padcpy mk/mv (1024..1279),
// bmatfill Wg1 (1280..2367), cvec (2368..2431). All independent.
// =================================================================
__global__ __launch_bounds__(256)
void prep1_k(const float* __restrict__ Wq, bf16* __restrict__ WqT,
             const float* __restrict__ mk, const float* __restrict__ mv,
             bf16* __restrict__ mkP, bf16* __restrict__ mvP,
             const float* __restrict__ Wg1, bf16* __restrict__ Bmat, bf16* __restrict__ W1b,
             const float* __restrict__ bq, float* __restrict__ cvec)
{
    __shared__ float T[64][72];
    __shared__ float wS[4];
    const int bid = blockIdx.x;
    const int t = threadIdx.x;

    if (bid < 1024) {
        const int bx = bid & 31, byy = bid >> 5;
        const int o0 = byy * 64, i0 = bx * 64;
        const int r = t >> 3, c8 = (t & 7) * 8;
#pragma unroll
        for (int rep = 0; rep < 2; ++rep) {
            int row = r + rep * 32;
            *(f32x4*)&T[row][c8]     = *(const f32x4*)&Wq[(size_t)(o0 + row) * HH + i0 + c8];
            *(f32x4*)&T[row][c8 + 4] = *(const f32x4*)&Wq[(size_t)(o0 + row) * HH + i0 + c8 + 4];
        }
        __syncthreads();
#pragma unroll
        for (int rep = 0; rep < 2; ++rep) {
            int irow = r + rep * 32;
            bf16x8 v;
#pragma unroll
            for (int jj = 0; jj < 8; ++jj) v[jj] = (bf16)T[c8 + jj][irow];
            *(bf16x8*)&WqT[(size_t)(i0 + irow) * HH + o0 + c8] = v;
        }
    } else if (bid < 1280) {
        int idx = ((bid - 1024) * 256 + t) * 8;
        const int half = 128 * HH;
        const float* s; bf16* d; int i;
        if (idx < half) { i = idx; d = mkP; s = mk; }
        else            { i = idx - half; d = mvP; s = mv; }
        bf16x8 v = {};
        if (i < MM * HH) {
            f32x4 a = *(const f32x4*)&s[i];
            f32x4 b = *(const f32x4*)&s[i + 4];
            v = cvt8(a, b);
        }
        *(bf16x8*)&d[i] = v;
    } else if (bid < 2368) {
        int row = 64 + (bid - 1280);
        int c8  = t * 8;
        int j   = row - 64;
        bf16x8 v = {};
        if (j < NHID) {
            f32x4 a = *(const f32x4*)&Wg1[(size_t)j * 4096 + c8];
            f32x4 b = *(const f32x4*)&Wg1[(size_t)j * 4096 + c8 + 4];
            v = cvt8(a, b);
            f32x4 c = *(const f32x4*)&Wg1[(size_t)j * 4096 + 2048 + c8];
            f32x4 d = *(const f32x4*)&Wg1[(size_t)j * 4096 + 2048 + c8 + 4];
            *(bf16x8*)&W1b[(size_t)j * HH + c8] = cvt8(c, d);
        }
        *(bf16x8*)&Bmat[(size_t)row * HH + c8] = v;
    } else {
        const int m = bid - 2368, wid = t >> 6, lane = t & 63;
        const int o0 = t * 8;
        f32x4 b0 = *(const f32x4*)&bq[o0];
        f32x4 b1 = *(const f32x4*)&bq[o0 + 4];
        f32x4 k0 = *(const f32x4*)&mk[(size_t)m * HH + o0];
        f32x4 k1 = *(const f32x4*)&mk[(size_t)m * HH + o0 + 4];
        float acc = b0[0]*k0[0] + b0[1]*k0[1] + b0[2]*k0[2] + b0[3]*k0[3]
                  + b1[0]*k1[0] + b1[1]*k1[1] + b1[2]*k1[2] + b1[3]*k1[3];
        acc = wave_sum(acc);
        if (lane == 0) wS[wid] = acc;
        __syncthreads();
        if (t == 0) cvec[m] = wS[0] + wS[1] + wS[2] + wS[3];
    }
}

// merged: Pf->Bmat rows 0..63 ; Q2f -> q2t (transposed bf16) ; mv -> mvT
__global__ __launch_bounds__(256)
void prep2_k(const float* __restrict__ Pf, bf16* __restrict__ Bmat,
             const float* __restrict__ Q2f, const float* __restrict__ mv,
             bf16* __restrict__ q2t, bf16* __restrict__ mvT)
{
    int gid = blockIdx.x * 256 + threadIdx.x;
    if (gid < 16384) {
        int idx = gid * 8;
        f32x4 a = *(const f32x4*)&Pf[idx];
        f32x4 b = *(const f32x4*)&Pf[idx + 4];
        *(bf16x8*)&Bmat[idx] = cvt8(a, b);
    } else if (gid < 16384 + NHID * MM) {
        int idx = gid - 16384;
        int j = idx >> 6, m = idx & 63;
        q2t[idx] = (bf16)Q2f[(size_t)m * NHID + j];
    } else {
        int i = gid - 16384 - NHID * MM;
        int h = i >> 6, m = i & 63;
        mvT[i] = (bf16)mv[(size_t)m * HH + h];
    }
}

// =================================================================
// epi A (phases 1-3): softmax, gate, retrieved MFMA + fuse -> fz +
// LN stats -> statsG + xpart.  32 rows/block, 512 blocks, setprio.
// =================================================================
__global__ __launch_bounds__(256)
void epia_k(const bf16* __restrict__ Cb, const float* __restrict__ cvec,
            const bf16* __restrict__ mvT, const bf16* __restrict__ q2t,
            const float* __restrict__ chs,
            const float* __restrict__ bg1, const float* __restrict__ w2,
            const float* __restrict__ bg2,
            float* __restrict__ out, bf16* __restrict__ xpart,
            bf16* __restrict__ fz, float* __restrict__ statsG)
{
    __shared__ __align__(16) bf16 attnB[32 * 64];
    __shared__ float redA[4][32], redB[4][32];
    __shared__ float gS[32];
    const int t = threadIdx.x, wid = t >> 6, lane = t & 63;
    const size_t row0 = (size_t)blockIdx.x * 32;
    const int cl = lane & 15;
    const int rbase = (lane >> 4) * 4;

    // ---- phase 1: softmax; wave w -> rows 8w..8w+7
    {
        float cv = cvec[lane];
#pragma unroll
        for (int rr = 0; rr < 8; ++rr) {
            int r = wid * 8 + rr;
            float s = (float)Cb[(row0 + r) * NC + lane] + cv;
            float mx = s;
#pragma unroll
            for (int off = 32; off; off >>= 1) mx = fmaxf(mx, __shfl_xor(mx, off));
            float e = expf(s - mx);
            float sum = e;
#pragma unroll
            for (int off = 32; off; off >>= 1) sum += __shfl_xor(sum, off);
            attnB[r * 64 + lane] = (bf16)(e / sum);
        }
    }
    __syncthreads();

    bf16x8 av00 = *(const bf16x8*)&attnB[(cl)      * 64 +  0 + (lane >> 4) * 8];
    bf16x8 av01 = *(const bf16x8*)&attnB[(cl)      * 64 + 32 + (lane >> 4) * 8];
    bf16x8 av10 = *(const bf16x8*)&attnB[(16 + cl) * 64 +  0 + (lane >> 4) * 8];
    bf16x8 av11 = *(const bf16x8*)&attnB[(16 + cl) * 64 + 32 + (lane >> 4) * 8];

    // ---- phase 2: gate
    {
        float gp[2][4] = {};
#pragma unroll
        for (int nt = 0; nt < 16; ++nt) {
            int ct = wid * 256 + nt * 16 + cl;
            bf16x8 bv0 = *(const bf16x8*)&q2t[(size_t)ct * 64 +  0 + (lane >> 4) * 8];
            bf16x8 bv1 = *(const bf16x8*)&q2t[(size_t)ct * 64 + 32 + (lane >> 4) * 8];
            float b1 = bg1[ct], wv = w2[ct];
            f32x4 a0 = {}, a1 = {};
            __builtin_amdgcn_s_setprio(1);
            a0 = __builtin_amdgcn_mfma_f32_16x16x32_bf16(av00, bv0, a0, 0, 0, 0);
            a0 = __builtin_amdgcn_mfma_f32_16x16x32_bf16(av01, bv1, a0, 0, 0, 0);
            a1 = __builtin_amdgcn_mfma_f32_16x16x32_bf16(av10, bv0, a1, 0, 0, 0);
            a1 = __builtin_amdgcn_mfma_f32_16x16x32_bf16(av11, bv1, a1, 0, 0, 0);
            __builtin_amdgcn_s_setprio(0);
#pragma unroll
            for (int j = 0; j < 4; ++j) {
                float c0 = (float)Cb[(row0 + rbase + j) * NC + 64 + ct];
                float c1 = (float)Cb[(row0 + 16 + rbase + j) * NC + 64 + ct];
                gp[0][j] += fmaxf(c0 + b1 + a0[j], 0.f) * wv;
                gp[1][j] += fmaxf(c1 + b1 + a1[j], 0.f) * wv;
            }
        }
#pragma unroll
        for (int g = 0; g < 2; ++g)
#pragma unroll
            for (int j = 0; j < 4; ++j) {
                gp[g][j] += __shfl_xor(gp[g][j], 1);
                gp[g][j] += __shfl_xor(gp[g][j], 2);
                gp[g][j] += __shfl_xor(gp[g][j], 4);
                gp[g][j] += __shfl_xor(gp[g][j], 8);
            }
        if (cl == 0) {
#pragma unroll
            for (int g = 0; g < 2; ++g)
#pragma unroll
                for (int j = 0; j < 4; ++j) redA[wid][g * 16 + rbase + j] = gp[g][j];
        }
    }
    __syncthreads();
    if (t < 32) {
        float g = redA[0][t] + redA[1][t] + redA[2][t] + redA[3][t];
        g = 1.f / (1.f + expf(-(g + bg2[0])));
        gS[t] = g;
        out[O_GATE + row0 + t] = g;
    }
    __syncthreads();

    float gR[2][4], omR[2][4];
#pragma unroll
    for (int g = 0; g < 2; ++g)
#pragma unroll
        for (int j = 0; j < 4; ++j) { gR[g][j] = gS[g * 16 + rbase + j]; omR[g][j] = 1.f - gR[g][j]; }

    // ---- phase 3: retrieved MFMA + fuse -> fz + LN stats + xpart
    {
        float sA[2][4] = {}, qA[2][4] = {};
        for (int nt = 0; nt < 32; ++nt) {
            int ct = wid * 512 + nt * 16 + cl;
            bf16x8 bv0 = *(const bf16x8*)&mvT[(size_t)ct * 64 +  0 + (lane >> 4) * 8];
            bf16x8 bv1 = *(const bf16x8*)&mvT[(size_t)ct * 64 + 32 + (lane >> 4) * 8];
            f32x4 a0 = {}, a1 = {};
            __builtin_amdgcn_s_setprio(1);
            a0 = __builtin_amdgcn_mfma_f32_16x16x32_bf16(av00, bv0, a0, 0, 0, 0);
            a0 = __builtin_amdgcn_mfma_f32_16x16x32_bf16(av01, bv1, a0, 0, 0, 0);
            a1 = __builtin_amdgcn_mfma_f32_16x16x32_bf16(av10, bv0, a1, 0, 0, 0);
            a1 = __builtin_amdgcn_mfma_f32_16x16x32_bf16(av11, bv1, a1, 0, 0, 0);
            __builtin_amdgcn_s_setprio(0);
            float xc = 0.f;
#pragma unroll
            for (int j = 0; j < 4; ++j) {
                float x0 = chs[(row0 + rbase + j) * HH + ct];
                float x1 = chs[(row0 + 16 + rbase + j) * HH + ct];
                xc += x0 + x1;
                float f0 = omR[0][j] * x0 + gR[0][j] * a0[j];
                float f1 = omR[1][j] * x1 + gR[1][j] * a1[j];
                fz[(row0 + rbase + j) * HH + ct]      = (bf16)f0;
                fz[(row0 + 16 + rbase + j) * HH + ct] = (bf16)f1;
                sA[0][j] += f0; qA[0][j] += f0 * f0;
                sA[1][j] += f1; qA[1][j] += f1 * f1;
            }
            xc += __shfl_xor(xc, 16);
            xc += __shfl_xor(xc, 32);
            if (lane < 16) xpart[(size_t)blockIdx.x * 2048 + ct] = (bf16)xc;
        }
#pragma unroll
        for (int g = 0; g < 2; ++g)
#pragma unroll
            for (int j = 0; j < 4; ++j) {
                sA[g][j] += __shfl_xor(sA[g][j], 1); qA[g][j] += __shfl_xor(qA[g][j], 1);
                sA[g][j] += __shfl_xor(sA[g][j], 2); qA[g][j] += __shfl_xor(qA[g][j], 2);
                sA[g][j] += __shfl_xor(sA[g][j], 4); qA[g][j] += __shfl_xor(qA[g][j], 4);
                sA[g][j] += __shfl_xor(sA[g][j], 8); qA[g][j] += __shfl_xor(qA[g][j], 8);
            }
        if (cl == 0) {
#pragma unroll
            for (int g = 0; g < 2; ++g)
#pragma unroll
                for (int j = 0; j < 4; ++j) {
                    redA[wid][g * 16 + rbase + j] = sA[g][j];
                    redB[wid][g * 16 + rbase + j] = qA[g][j];
                }
        }
    }
    __syncthreads();
    if (t < 32) {
        float s = redA[0][t] + redA[1][t] + redA[2][t] + redA[3][t];
        float q = redB[0][t] + redB[1][t] + redB[2][t] + redB[3][t];
        float mu  = s * (1.f / 2048.f);
        float var = q * (1.f / 2048.f) - mu * mu;
        statsG[row0 + t]         = mu;
        statsG[ROWS + row0 + t]  = rsqrtf(var + 1e-5f);
    }
}

// =================================================================
// epi B: streaming LN. 2048 blocks x 256 thr, 8 rows/block.
// =================================================================
__global__ __launch_bounds__(256)
void epib_k(const bf16* __restrict__ fz, const float* __restrict__ statsG,
            const float* __restrict__ gamma, const float* __restrict__ beta,
            float* __restrict__ out)
{
    const int t = threadIdx.x;
    const size_t row0 = (size_t)blockIdx.x * 8;
    const int h0 = t * 8;
    f32x4 g0 = *(const f32x4*)&gamma[h0];
    f32x4 g1 = *(const f32x4*)&gamma[h0 + 4];
    f32x4 b0 = *(const f32x4*)&beta[h0];
    f32x4 b1 = *(const f32x4*)&beta[h0 + 4];
#pragma unroll
    for (int r = 0; r < 8; ++r) {
        float mu = statsG[row0 + r];
        float rs = statsG[ROWS + row0 + r];
        bf16x8 fv = *(const bf16x8*)&fz[(row0 + r) * HH + h0];
        f32x4 oa, ob;
#pragma unroll
        for (int jj = 0; jj < 4; ++jj) {
            oa[jj] = ((float)fv[jj]     - mu) * rs * g0[jj] + b0[jj];
            ob[jj] = ((float)fv[jj + 4] - mu) * rs * g1[jj] + b1[jj];
        }
        float* po = &out[O_OUT + (row0 + r) * HH + h0];
        *(f32x4*)po       = oa;
        *(f32x4*)(po + 4) = ob;
    }
}

// xbar[b][h] = sum over 128 block-partials (bf16) per batch
__global__ __launch_bounds__(256)
void xred_k(const bf16* __restrict__ xpart, float* __restrict__ xbar)
{
    int o = blockIdx.x * 256 + threadIdx.x;   // 0..8191
    int b = o >> 11, h = o & 2047;
    const bf16* p = xpart + (size_t)(b * 128) * 2048 + h;
    float acc = 0.f;
    for (int k = 0; k < 128; ++k) acc += (float)p[(size_t)k * 2048];
    xbar[o] = acc;
}

// kb/vb[b,h] = bias[h] + (1/4096) * sum_i xbar[b,i]*W[h,i]  (4-way i-split)
__global__ __launch_bounds__(256)
void kbvb_k(const float* __restrict__ xbar,
            const float* __restrict__ Wk, const float* __restrict__ bk,
            const float* __restrict__ Wv, const float* __restrict__ bv,
            float* __restrict__ kb, float* __restrict__ vb)
{
    int gt = blockIdx.x * 256 + threadIdx.x;    // 0..65535
    int out_idx = gt >> 2, part = gt & 3;
    int mat = out_idx >> 13, rem = out_idx & 8191;
    int b = rem >> 11, h = rem & 2047;
    const float* W    = mat ? Wv : Wk;
    const float* bias = mat ? bv : bk;
    const float* x    = xbar + b * HH;
    float acc = 0.f;
    const int i0 = part * 512;
    for (int i = i0; i < i0 + 512; i += 8) {
        f32x4 w0 = *(const f32x4*)&W[(size_t)h * HH + i];
        f32x4 w1 = *(const f32x4*)&W[(size_t)h * HH + i + 4];
        f32x4 x0 = *(const f32x4*)&x[i];
        f32x4 x1 = *(const f32x4*)&x[i + 4];
        acc += x0[0]*w0[0] + x0[1]*w0[1] + x0[2]*w0[2] + x0[3]*w0[3];
        acc += x1[0]*w1[0] + x1[1]*w1[1] + x1[2]*w1[2] + x1[3]*w1[3];
    }
    acc += __shfl_xor(acc, 1);
    acc += __shfl_xor(acc, 2);
    if (part == 0)
        (mat ? vb : kb)[b * HH + h] = bias[h] + acc * (1.f / 4096.f);
}

// copy mk/mv inputs (f32) to output slots (f32)
__global__ __launch_bounds__(256)
void copy_mkmv_k(const float* __restrict__ mk, const float* __restrict__ mv, float* __restrict__ out)
{
    int idx = (blockIdx.x * 256 + threadIdx.x) * 4;
    const int half = MM * HH;
    if (idx < half)
        *(f32x4*)&out[O_MK + idx] = *(const f32x4*)&mk[idx];
    else
        *(f32x4*)&out[O_MV + (idx - half)] = *(const f32x4*)&mv[idx - half];
}

// sequential argmin-scatter memory update (4 steps), single block
__global__ __launch_bounds__(256)
void scan_k(const int* __restrict__ uc_in, const int* __restrict__ ts_in,
            const float* __restrict__ kb, const float* __restrict__ vb,
            float* __restrict__ out)
{
    __shared__ int ucS[64], tsS[64];
    __shared__ int idxS, tmaxS;
    const int t = threadIdx.x;
    if (t < 64) { ucS[t] = uc_in[t]; tsS[t] = ts_in[t]; }
    __syncthreads();
    for (int b = 0; b < 4; ++b) {
        if (t < 64) {
            float bs = (float)ucS[t] + 0.1f * (float)tsS[t];
            int bi = t;
            int tm = tsS[t];
#pragma unroll
            for (int off = 1; off < 64; off <<= 1) {
                float os = __shfl_xor(bs, off);
                int   oi = __shfl_xor(bi, off);
                int   om = __shfl_xor(tm, off);
                if (os < bs || (os == bs && oi < bi)) { bs = os; bi = oi; }
                tm = max(tm, om);
            }
            if (t == 0) { idxS = bi; tmaxS = tm; }
        }
        __syncthreads();
        int idx = idxS;
        int e = t * 8;
        *(f32x4*)&out[O_MK + (size_t)idx * HH + e]     = *(const f32x4*)&kb[b * HH + e];
        *(f32x4*)&out[O_MK + (size_t)idx * HH + e + 4] = *(const f32x4*)&kb[b * HH + e + 4];
        *(f32x4*)&out[O_MV + (size_t)idx * HH + e]     = *(const f32x4*)&vb[b * HH + e];
        *(f32x4*)&out[O_MV + (size_t)idx * HH + e + 4] = *(const f32x4*)&vb[b * HH + e + 4];
        __syncthreads();
        if (t == 0) { ucS[idx] += 1; tsS[idx] = tmaxS + 1; }
        __syncthreads();
    }
    if (t < 64) {
        out[O_UC + t] = (float)ucS[t];
        out[O_TS + t] = (float)tsS[t];
    }
}

// =================================================================
extern "C" void kernel_launch(void* const* d_in, const int* in_sizes, int n_in,
                              void* d_out, int out_size, void* d_ws, size_t ws_size,
                              hipStream_t stream)
{
    const float* chs = (const float*)d_in[0];
    const float* xl  = (const float*)d_in[1];
    const float* mk  = (const float*)d_in[2];
    const float* mv  = (const float*)d_in[3];
    const float* Wq  = (const float*)d_in[4];
    const float* bq  = (const float*)d_in[5];
    const float* Wk  = (const float*)d_in[6];
    const float* bk  = (const float*)d_in[7];
    const float* Wv  = (const float*)d_in[8];
    const float* bv  = (const float*)d_in[9];
    const float* Wg1 = (const float*)d_in[10];
    const float* bg1 = (const float*)d_in[11];
    const float* Wg2 = (const float*)d_in[12];
    const float* bg2 = (const float*)d_in[13];
    const float* lng = (const float*)d_in[14];
    const float* lnb = (const float*)d_in[15];
    const int*   ucI = (const int*)d_in[16];
    const int*   tsI = (const int*)d_in[17];

    uint8_t* ws = (uint8_t*)d_ws;
    float* outp = (float*)d_out;

    bf16*  xlb  = (bf16*)(ws + WS_XLB);
    bf16*  fz   = (bf16*)(ws + WS_XLB);     // reuse: xlb dead after main GEMM
    bf16*  Cb   = (bf16*)(ws + WS_C);
    bf16*  Bmat = (bf16*)(ws + WS_BMAT);
    bf16*  WqT  = (bf16*)(ws + WS_WQT);
    bf16*  xpart= (bf16*)(ws + WS_WQT);     // reuse: WqT dead after P-GEMM
    bf16*  W1b  = (bf16*)(ws + WS_W1B);
    bf16*  mkP  = (bf16*)(ws + WS_MKP);
    bf16*  mvP  = (bf16*)(ws + WS_MVP);
    bf16*  q2t  = (bf16*)(ws + WS_Q2T);
    bf16*  mvT  = (bf16*)(ws + WS_MVT);
    float* Pf   = (float*)(ws + WS_PF);
    float* Q2f  = (float*)(ws + WS_Q2F);
    float* cvec = (float*)(ws + WS_CVEC);
    float* xbar = (float*)(ws + WS_XBAR);
    float* kb   = (float*)(ws + WS_KB);
    float* vb   = (float*)(ws + WS_VB);
    float* stats= (float*)(ws + WS_STAT);

    hipMemsetAsync(Pf, 0, (size_t)MM * HH * 4, stream);
    hipMemsetAsync(Q2f, 0, (size_t)MM * NHID * 4, stream);

    conv_xl_k<<<16384, 256, 0, stream>>>(xl, xlb);
    prep1_k<<<2432, 256, 0, stream>>>(Wq, WqT, mk, mv, mkP, mvP, Wg1, Bmat, W1b, bq, cvec);

    // P = mkPad @ Wq  (split-K, f32 atomic)
    gemm_bt<true, false><<<dim3(1, 16, 8), 256, 0, stream>>>(mkP, HH, WqT, HH, Pf, HH, MM, 4);
    // Q2 = mvPad @ Wg1b^T
    gemm_bt<true, false><<<dim3(1, 8, 8), 256, 0, stream>>>(mvP, HH, W1b, HH, Q2f, NHID, MM, 4);
    prep2_k<<<832, 256, 0, stream>>>(Pf, Bmat, Q2f, mv, q2t, mvT);

    // main fused GEMM: [16384,2048] @ [2048,1152]  (XCD-chunked remap)
    gemm_bt<false, true><<<1152, 256, 0, stream>>>(xlb, HH, Bmat, HH, Cb, NC, ROWS, 32);

    epia_k<<<512, 256, 0, stream>>>(Cb, cvec, mvT, q2t, chs, bg1, Wg2, bg2, outp, xpart, fz, stats);
    epib_k<<<2048, 256, 0, stream>>>(fz, stats, lng, lnb, outp);

    xred_k<<<32, 256, 0, stream>>>(xpart, xbar);
    kbvb_k<<<256, 256, 0, stream>>>(xbar, Wk, bk, Wv, bv, kb, vb);
    copy_mkmv_k<<<256, 256, 0, stream>>>(mk, mv, outp);
    scan_k<<<1, 256, 0, stream>>>(ucI, tsI, kb, vb, outp);
}